// Round 4
// baseline (3508.266 us; speedup 1.0000x reference)
//
#include <hip/hip_runtime.h>

#define NN 4096
#define DD 128
#define REGC 0.05f
#define EPSC 1e-8f
#define NSINK 14
#define KPAD 144  // shorts; 288B row stride -> max 4-way LDS bank conflict on frag reads

typedef float f32x4 __attribute__((ext_vector_type(4)));
typedef float f32x2 __attribute__((ext_vector_type(2)));
typedef short s16x8 __attribute__((ext_vector_type(8)));

__device__ __forceinline__ float wave_reduce_sum(float s) {
#pragma unroll
  for (int m = 32; m >= 1; m >>= 1) s += __shfl_xor(s, m, 64);
  return s;
}

__device__ __forceinline__ short f32_to_bf16(float f) {
  union { float f; unsigned u; } x; x.f = f;
  unsigned r = (x.u + 0x7FFFu + ((x.u >> 16) & 1u)) >> 16;
  return (short)r;
}

__device__ __forceinline__ void fp8x4_decode(unsigned int k, float* o) {
  f32x2 lo = __builtin_amdgcn_cvt_pk_f32_fp8((int)k, false);
  f32x2 hi = __builtin_amdgcn_cvt_pk_f32_fp8((int)k, true);
  o[0] = lo[0]; o[1] = lo[1]; o[2] = hi[0]; o[3] = hi[1];
}

__device__ __forceinline__ void fp8x16_decode(uint4 k, float* o) {
  fp8x4_decode(k.x, o); fp8x4_decode(k.y, o + 4);
  fp8x4_decode(k.z, o + 8); fp8x4_decode(k.w, o + 12);
}

// dot of 16 fp8 with v held as 4 f32x4
__device__ __forceinline__ float dot16v(uint4 k, f32x4 v0, f32x4 v1, f32x4 v2, f32x4 v3) {
  float o[16];
  fp8x16_decode(k, o);
  float s = 0.f;
#pragma unroll
  for (int j = 0; j < 4; j++) s += o[j] * v0[j];
#pragma unroll
  for (int j = 0; j < 4; j++) s += o[4 + j] * v1[j];
#pragma unroll
  for (int j = 0; j < 4; j++) s += o[8 + j] * v2[j];
#pragma unroll
  for (int j = 0; j < 4; j++) s += o[12 + j] * v3[j];
  return s;
}

// grid 12288 (zi*4096+row), block 128: row norms + bf16 convert
__global__ __launch_bounds__(128) void prep_kernel(const float* __restrict__ z0, const float* __restrict__ z1,
                                                   const float* __restrict__ z2, short* __restrict__ zb,
                                                   float* __restrict__ sq) {
  int row = blockIdx.x;
  int zi = row >> 12;
  const float* z = (zi == 0) ? z0 : ((zi == 1) ? z1 : z2);
  int r = row & (NN - 1);
  float val = z[r * DD + threadIdx.x];
  zb[row * DD + threadIdx.x] = f32_to_bf16(val);
  float s = wave_reduce_sum(val * val);
  __shared__ float red[2];
  if ((threadIdx.x & 63) == 0) red[threadIdx.x >> 6] = s;
  __syncthreads();
  if (threadIdx.x == 0) sq[row] = red[0] + red[1];
}

// grid dim3(32,32,3), block 256: 128x128 tile via LDS-staged MFMA; K=fp8(exp(-C/reg));
// epilogue accumulates column sums into t0 (pre-zeroed) => t0 = K^T * ones (t for u0=1)
__global__ __launch_bounds__(256) void kbuild_kernel(const short* __restrict__ zb, const float* __restrict__ sq,
                                                     unsigned char* __restrict__ K, float* __restrict__ t0) {
  int p = blockIdx.z;
  int ai = (p == 2) ? 1 : 0;            // pairs (0,1),(0,2),(1,2)
  int bi = (p == 0) ? 1 : 2;
  const short* xg = zb + ai * NN * DD + blockIdx.y * 128 * DD;
  const short* yg = zb + bi * NN * DD + blockIdx.x * 128 * DD;
  const float* sqx = sq + ai * NN + blockIdx.y * 128;
  const float* sqy = sq + bi * NN + blockIdx.x * 128;
  __shared__ short xs[128 * KPAD];
  __shared__ short ys[128 * KPAD];
  __shared__ float colsum[128];
  int tid = threadIdx.x;
  for (int i = tid; i < 2048; i += 256) {
    int row = i >> 4, seg = i & 15;
    *(uint4*)&xs[row * KPAD + seg * 8] = *(const uint4*)&xg[row * DD + seg * 8];
    *(uint4*)&ys[row * KPAD + seg * 8] = *(const uint4*)&yg[row * DD + seg * 8];
  }
  if (tid < 128) colsum[tid] = 0.f;
  __syncthreads();
  int w = tid >> 6, lane = tid & 63;
  int wr = (w >> 1) * 64, wc = (w & 1) * 64;
  int lrow = lane & 15, lk = lane >> 4;
  f32x4 acc[4][4];
#pragma unroll
  for (int i = 0; i < 4; i++)
#pragma unroll
    for (int j = 0; j < 4; j++) acc[i][j] = (f32x4){0.f, 0.f, 0.f, 0.f};
#pragma unroll
  for (int kk = 0; kk < 4; kk++) {
    s16x8 a[4], b[4];
#pragma unroll
    for (int rt = 0; rt < 4; rt++) {
      a[rt] = *(const s16x8*)&xs[(wr + rt * 16 + lrow) * KPAD + kk * 32 + lk * 8];
      b[rt] = *(const s16x8*)&ys[(wc + rt * 16 + lrow) * KPAD + kk * 32 + lk * 8];
    }
#pragma unroll
    for (int rt = 0; rt < 4; rt++)
#pragma unroll
      for (int ct = 0; ct < 4; ct++)
        acc[rt][ct] = __builtin_amdgcn_mfma_f32_16x16x32_bf16(a[rt], b[ct], acc[rt][ct], 0, 0, 0);
  }
  unsigned char* Kp = K + (size_t)p * NN * NN;
#pragma unroll
  for (int ct = 0; ct < 4; ct++) {
    int coll = wc + ct * 16 + lrow;
    int colg = blockIdx.x * 128 + coll;
    float sy = sqy[coll];
    float cs = 0.f;
#pragma unroll
    for (int rt = 0; rt < 4; rt++) {
#pragma unroll
      for (int r = 0; r < 4; r++) {
        int rowl = wr + rt * 16 + lk * 4 + r;
        float Cv = fmaxf(sqx[rowl] + sy - 2.0f * acc[rt][ct][r], 0.0f);
        float kf = __expf(Cv * (-1.0f / REGC));
        cs += kf;
        int pk = __builtin_amdgcn_cvt_pk_fp8_f32(kf, kf, 0, false);
        Kp[(size_t)(blockIdx.y * 128 + rowl) * NN + colg] = (unsigned char)(pk & 0xFF);
      }
    }
    cs += __shfl_xor(cs, 16, 64);
    cs += __shfl_xor(cs, 32, 64);
    if (lk == 0) atomicAdd(&colsum[coll], cs);
  }
  __syncthreads();
  if (tid < 128) atomicAdd(&t0[p * NN + blockIdx.x * 128 + tid], colsum[tid]);
}

// grid 768 (p*256+rb), block 256, 16 rows/block. One full Sinkhorn iteration, one pass over K:
//   A: v = nu/(tin+eps) -> LDS (swizzled); zero tzero slice
//   B: u = mu/(K v + eps) for the block's 16 rows (4 rows/wave, v amortized over 4 rows)
//   C: tadd[col] += sum_{rows} K[row][col] * u[row] (thread owns 16 cols, 1 atomic/col)
__global__ __launch_bounds__(256) void sink_fused(const unsigned char* __restrict__ K,
                                                  const float* __restrict__ tin, float* __restrict__ tadd,
                                                  float* __restrict__ tzero, float* __restrict__ u) {
  int bid = blockIdx.x;
  int p = bid >> 8;
  int rb = bid & 255;
  int tid = threadIdx.x;
  int w = tid >> 6, lane = tid & 63;
  __shared__ float vswz[NN];   // swizzled: v[col], col = c*1024 + lane*16 + q*4 + j  at [((c*4+q)*64+lane)*4 + j]
  __shared__ float ulds[16];
  const float* tp = tin + p * NN;
  if (tid < 16) tzero[bid * 16 + tid] = 0.f;
  {
    int c = tid >> 6;
#pragma unroll
    for (int q = 0; q < 4; q++) {
      f32x4 tv = *(const f32x4*)&tp[c * 1024 + lane * 16 + q * 4];
      f32x4 o;
#pragma unroll
      for (int j = 0; j < 4; j++) o[j] = (1.0f / NN) * __builtin_amdgcn_rcpf(tv[j] + EPSC);
      *(f32x4*)&vswz[((c * 4 + q) * 64 + lane) * 4] = o;
    }
  }
  __syncthreads();
  const unsigned char* Kp = K + (size_t)p * NN * NN;
  int r0 = rb * 16;
  // phase B: rows r0 + w*4 .. +3
  {
    const unsigned char* kbase = Kp + (size_t)(r0 + w * 4) * NN + lane * 16;
    float acc0 = 0.f, acc1 = 0.f, acc2 = 0.f, acc3 = 0.f;
#pragma unroll
    for (int c = 0; c < 4; c++) {
      uint4 k0 = *(const uint4*)(kbase + c * 1024);
      uint4 k1 = *(const uint4*)(kbase + (size_t)NN + c * 1024);
      uint4 k2 = *(const uint4*)(kbase + (size_t)2 * NN + c * 1024);
      uint4 k3 = *(const uint4*)(kbase + (size_t)3 * NN + c * 1024);
      f32x4 v0 = *(const f32x4*)&vswz[((c * 4 + 0) * 64 + lane) * 4];
      f32x4 v1 = *(const f32x4*)&vswz[((c * 4 + 1) * 64 + lane) * 4];
      f32x4 v2 = *(const f32x4*)&vswz[((c * 4 + 2) * 64 + lane) * 4];
      f32x4 v3 = *(const f32x4*)&vswz[((c * 4 + 3) * 64 + lane) * 4];
      acc0 += dot16v(k0, v0, v1, v2, v3);
      acc1 += dot16v(k1, v0, v1, v2, v3);
      acc2 += dot16v(k2, v0, v1, v2, v3);
      acc3 += dot16v(k3, v0, v1, v2, v3);
    }
    acc0 = wave_reduce_sum(acc0);
    acc1 = wave_reduce_sum(acc1);
    acc2 = wave_reduce_sum(acc2);
    acc3 = wave_reduce_sum(acc3);
    if (lane == 0) {
      float u0 = (1.0f / NN) / (acc0 + EPSC);
      float u1 = (1.0f / NN) / (acc1 + EPSC);
      float u2 = (1.0f / NN) / (acc2 + EPSC);
      float u3 = (1.0f / NN) / (acc3 + EPSC);
      ulds[w * 4 + 0] = u0; ulds[w * 4 + 1] = u1;
      ulds[w * 4 + 2] = u2; ulds[w * 4 + 3] = u3;
      float* ug = u + p * NN + r0 + w * 4;
      ug[0] = u0; ug[1] = u1; ug[2] = u2; ug[3] = u3;
    }
  }
  __syncthreads();
  // phase C: thread owns cols tid*16..+15 over the block's 16 rows (L2-warm)
  float ca[16];
#pragma unroll
  for (int j = 0; j < 16; j++) ca[j] = 0.f;
  const unsigned char* kc = Kp + (size_t)r0 * NN + tid * 16;
#pragma unroll 4
  for (int r = 0; r < 16; r++) {
    uint4 k = *(const uint4*)(kc + (size_t)r * NN);
    float ur = ulds[r];
    float kd[16];
    fp8x16_decode(k, kd);
#pragma unroll
    for (int j = 0; j < 16; j++) ca[j] += kd[j] * ur;
  }
  float* td = tadd + p * NN + tid * 16;
#pragma unroll
  for (int j = 0; j < 16; j++) atomicAdd(&td[j], ca[j]);
}

// grid 768 (p*256+rb), block 256, 16 rows/block: loss += u_i K_ij v_j C_ij, C=-reg*ln(K)
__global__ __launch_bounds__(256) void loss_kernel(const unsigned char* __restrict__ K,
                                                   const float* __restrict__ tin, const float* __restrict__ u,
                                                   float* __restrict__ out) {
  int bid = blockIdx.x;
  int p = bid >> 8;
  int rb = bid & 255;
  int tid = threadIdx.x;
  int w = tid >> 6, lane = tid & 63;
  __shared__ float vswz[NN];
  const float* tp = tin + p * NN;
  {
    int c = tid >> 6;
#pragma unroll
    for (int q = 0; q < 4; q++) {
      f32x4 tv = *(const f32x4*)&tp[c * 1024 + lane * 16 + q * 4];
      f32x4 o;
#pragma unroll
      for (int j = 0; j < 4; j++) o[j] = (1.0f / NN) * __builtin_amdgcn_rcpf(tv[j] + EPSC);
      *(f32x4*)&vswz[((c * 4 + q) * 64 + lane) * 4] = o;
    }
  }
  __syncthreads();
  const unsigned char* Kp = K + (size_t)p * NN * NN;
  const float* up = u + p * NN;
  int r0 = rb * 16;
  const unsigned char* kbase = Kp + (size_t)(r0 + w * 4) * NN + lane * 16;
  float acc0 = 0.f, acc1 = 0.f, acc2 = 0.f, acc3 = 0.f;
#pragma unroll
  for (int c = 0; c < 4; c++) {
    uint4 kr[4];
    kr[0] = *(const uint4*)(kbase + c * 1024);
    kr[1] = *(const uint4*)(kbase + (size_t)NN + c * 1024);
    kr[2] = *(const uint4*)(kbase + (size_t)2 * NN + c * 1024);
    kr[3] = *(const uint4*)(kbase + (size_t)3 * NN + c * 1024);
    f32x4 vq[4];
#pragma unroll
    for (int q = 0; q < 4; q++) vq[q] = *(const f32x4*)&vswz[((c * 4 + q) * 64 + lane) * 4];
#pragma unroll
    for (int r = 0; r < 4; r++) {
      float kd[16];
      fp8x16_decode(kr[r], kd);
      float racc = 0.f;
#pragma unroll
      for (int q = 0; q < 4; q++)
#pragma unroll
        for (int j = 0; j < 4; j++) {
          float kf = kd[q * 4 + j];
          racc += kf * vq[q][j] * (-REGC * __logf(kf));
        }
      if (r == 0) acc0 += racc;
      else if (r == 1) acc1 += racc;
      else if (r == 2) acc2 += racc;
      else acc3 += racc;
    }
  }
  float lt = acc0 * up[r0 + w * 4] + acc1 * up[r0 + w * 4 + 1] +
             acc2 * up[r0 + w * 4 + 2] + acc3 * up[r0 + w * 4 + 3];
  lt = wave_reduce_sum(lt);
  __shared__ float red[4];
  if (lane == 0) red[w] = lt;
  __syncthreads();
  if (tid == 0) atomicAdd(out, (red[0] + red[1] + red[2] + red[3]) * (1.0f / 3.0f));
}

extern "C" void kernel_launch(void* const* d_in, const int* in_sizes, int n_in,
                              void* d_out, int out_size, void* d_ws, size_t ws_size,
                              hipStream_t stream) {
  const float* z0 = (const float*)d_in[0];
  const float* z1 = (const float*)d_in[1];
  const float* z2 = (const float*)d_in[2];
  float* out = (float*)d_out;
  char* ws = (char*)d_ws;

  const size_t K_BYTES = (size_t)3 * NN * NN;            // 50331648 (fp8)
  unsigned char* K = (unsigned char*)ws;
  short* zb = (short*)(ws + K_BYTES);                    // 3145728 B
  float* sq = (float*)(ws + K_BYTES + 3145728);          // 49152 B
  float* u = (float*)(ws + K_BYTES + 3145728 + 49152);   // 49152 B
  float* tb = (float*)(ws + K_BYTES + 3145728 + 2 * 49152);  // 3 bufs x 3 pairs x 4096 f32

  hipMemsetAsync(d_out, 0, sizeof(float), stream);
  hipMemsetAsync(tb, 0, 3 * 3 * NN * sizeof(float), stream);

  prep_kernel<<<3 * NN, 128, 0, stream>>>(z0, z1, z2, zb, sq);
  kbuild_kernel<<<dim3(32, 32, 3), 256, 0, stream>>>(zb, sq, K, tb /* buf0 = t for u=1 */);

  // 3-buffer rotation: iter i reads buf[i%3], adds into buf[(i+1)%3] (pre-zeroed),
  // zeroes buf[(i+2)%3]
  for (int i = 0; i < NSINK; i++) {
    float* tin = tb + (size_t)(i % 3) * 3 * NN;
    float* tadd = tb + (size_t)((i + 1) % 3) * 3 * NN;
    float* tzero = tb + (size_t)((i + 2) % 3) * 3 * NN;
    sink_fused<<<768, 256, 0, stream>>>(K, tin, tadd, tzero, u);
  }
  // final v comes from the t-buffer the last iteration READ
  float* tlast = tb + (size_t)((NSINK - 1) % 3) * 3 * NN;
  loss_kernel<<<768, 256, 0, stream>>>(K, tlast, u, out);
}

// Round 5
// 468.366 us; speedup vs baseline: 7.4904x; 7.4904x over previous
//
#include <hip/hip_runtime.h>

#define NN 4096
#define DD 128
#define REGC 0.05f
#define EPSC 1e-8f
#define NSINK 12
#define KPAD 144  // shorts; 288B row stride

typedef float f32x4 __attribute__((ext_vector_type(4)));
typedef float f32x2 __attribute__((ext_vector_type(2)));
typedef short s16x8 __attribute__((ext_vector_type(8)));

__device__ __forceinline__ float wave_reduce_sum(float s) {
#pragma unroll
  for (int m = 32; m >= 1; m >>= 1) s += __shfl_xor(s, m, 64);
  return s;
}

__device__ __forceinline__ short f32_to_bf16(float f) {
  union { float f; unsigned u; } x; x.f = f;
  unsigned r = (x.u + 0x7FFFu + ((x.u >> 16) & 1u)) >> 16;
  return (short)r;
}

__device__ __forceinline__ void fp8x4_decode(unsigned int k, float* o) {
  f32x2 lo = __builtin_amdgcn_cvt_pk_f32_fp8((int)k, false);
  f32x2 hi = __builtin_amdgcn_cvt_pk_f32_fp8((int)k, true);
  o[0] = lo[0]; o[1] = lo[1]; o[2] = hi[0]; o[3] = hi[1];
}

__device__ __forceinline__ void fp8x16_decode(uint4 k, float* o) {
  fp8x4_decode(k.x, o); fp8x4_decode(k.y, o + 4);
  fp8x4_decode(k.z, o + 8); fp8x4_decode(k.w, o + 12);
}

__device__ __forceinline__ float dot16v(uint4 k, f32x4 v0, f32x4 v1, f32x4 v2, f32x4 v3) {
  float o[16];
  fp8x16_decode(k, o);
  float s = 0.f;
#pragma unroll
  for (int j = 0; j < 4; j++) s += o[j] * v0[j];
#pragma unroll
  for (int j = 0; j < 4; j++) s += o[4 + j] * v1[j];
#pragma unroll
  for (int j = 0; j < 4; j++) s += o[8 + j] * v2[j];
#pragma unroll
  for (int j = 0; j < 4; j++) s += o[12 + j] * v3[j];
  return s;
}

// grid 12288 (zi*4096+row), block 128: row norms + bf16 convert
__global__ __launch_bounds__(128) void prep_kernel(const float* __restrict__ z0, const float* __restrict__ z1,
                                                   const float* __restrict__ z2, short* __restrict__ zb,
                                                   float* __restrict__ sq) {
  int row = blockIdx.x;
  int zi = row >> 12;
  const float* z = (zi == 0) ? z0 : ((zi == 1) ? z1 : z2);
  int r = row & (NN - 1);
  float val = z[r * DD + threadIdx.x];
  zb[row * DD + threadIdx.x] = f32_to_bf16(val);
  float s = wave_reduce_sum(val * val);
  __shared__ float red[2];
  if ((threadIdx.x & 63) == 0) red[threadIdx.x >> 6] = s;
  __syncthreads();
  if (threadIdx.x == 0) sq[row] = red[0] + red[1];
}

// grid dim3(32,32,3), block 256: 128x128 tile via LDS-staged MFMA; K=fp8(exp(-C/reg));
// epilogue adds column sums into t_part chunk0 (pre-zeroed) => t for u0=1 (only ~12K atomics total)
__global__ __launch_bounds__(256) void kbuild_kernel(const short* __restrict__ zb, const float* __restrict__ sq,
                                                     unsigned char* __restrict__ K, float* __restrict__ t0) {
  int p = blockIdx.z;
  int ai = (p == 2) ? 1 : 0;            // pairs (0,1),(0,2),(1,2)
  int bi = (p == 0) ? 1 : 2;
  const short* xg = zb + ai * NN * DD + blockIdx.y * 128 * DD;
  const short* yg = zb + bi * NN * DD + blockIdx.x * 128 * DD;
  const float* sqx = sq + ai * NN + blockIdx.y * 128;
  const float* sqy = sq + bi * NN + blockIdx.x * 128;
  __shared__ short xs[128 * KPAD];
  __shared__ short ys[128 * KPAD];
  __shared__ float colsum[128];
  int tid = threadIdx.x;
  for (int i = tid; i < 2048; i += 256) {
    int row = i >> 4, seg = i & 15;
    *(uint4*)&xs[row * KPAD + seg * 8] = *(const uint4*)&xg[row * DD + seg * 8];
    *(uint4*)&ys[row * KPAD + seg * 8] = *(const uint4*)&yg[row * DD + seg * 8];
  }
  if (tid < 128) colsum[tid] = 0.f;
  __syncthreads();
  int w = tid >> 6, lane = tid & 63;
  int wr = (w >> 1) * 64, wc = (w & 1) * 64;
  int lrow = lane & 15, lk = lane >> 4;
  f32x4 acc[4][4];
#pragma unroll
  for (int i = 0; i < 4; i++)
#pragma unroll
    for (int j = 0; j < 4; j++) acc[i][j] = (f32x4){0.f, 0.f, 0.f, 0.f};
#pragma unroll
  for (int kk = 0; kk < 4; kk++) {
    s16x8 a[4], b[4];
#pragma unroll
    for (int rt = 0; rt < 4; rt++) {
      a[rt] = *(const s16x8*)&xs[(wr + rt * 16 + lrow) * KPAD + kk * 32 + lk * 8];
      b[rt] = *(const s16x8*)&ys[(wc + rt * 16 + lrow) * KPAD + kk * 32 + lk * 8];
    }
#pragma unroll
    for (int rt = 0; rt < 4; rt++)
#pragma unroll
      for (int ct = 0; ct < 4; ct++)
        acc[rt][ct] = __builtin_amdgcn_mfma_f32_16x16x32_bf16(a[rt], b[ct], acc[rt][ct], 0, 0, 0);
  }
  unsigned char* Kp = K + (size_t)p * NN * NN;
#pragma unroll
  for (int ct = 0; ct < 4; ct++) {
    int coll = wc + ct * 16 + lrow;
    int colg = blockIdx.x * 128 + coll;
    float sy = sqy[coll];
    float cs = 0.f;
#pragma unroll
    for (int rt = 0; rt < 4; rt++) {
#pragma unroll
      for (int r = 0; r < 4; r++) {
        int rowl = wr + rt * 16 + lk * 4 + r;
        float Cv = fmaxf(sqx[rowl] + sy - 2.0f * acc[rt][ct][r], 0.0f);
        float kf = __expf(Cv * (-1.0f / REGC));
        cs += kf;
        int pk = __builtin_amdgcn_cvt_pk_fp8_f32(kf, kf, 0, false);
        Kp[(size_t)(blockIdx.y * 128 + rowl) * NN + colg] = (unsigned char)(pk & 0xFF);
      }
    }
    cs += __shfl_xor(cs, 16, 64);
    cs += __shfl_xor(cs, 32, 64);
    if (lk == 0) atomicAdd(&colsum[coll], cs);
  }
  __syncthreads();
  if (tid < 128) atomicAdd(&t0[p * NN + blockIdx.x * 128 + tid], colsum[tid]);
}

// grid 768 (p*256+rb), block 256, 16 rows/block:
//   A: v = nu/(t_part[0]+t_part[1]+eps) -> LDS (swizzled)
//   B: u = mu/(K v + eps) for the block's 16 rows (4 rows/wave)
__global__ __launch_bounds__(256) void sink_u(const unsigned char* __restrict__ K,
                                              const float* __restrict__ t_part, float* __restrict__ u) {
  int bid = blockIdx.x;
  int p = bid >> 8;
  int rb = bid & 255;
  int tid = threadIdx.x;
  int w = tid >> 6, lane = tid & 63;
  __shared__ float vswz[NN];   // v[col], col = c*1024 + lane*16 + q*4 + j  at [((c*4+q)*64+lane)*4 + j]
  {
    int c = tid >> 6;
#pragma unroll
    for (int q = 0; q < 4; q++) {
      int idx = c * 1024 + lane * 16 + q * 4;
      f32x4 ta = *(const f32x4*)&t_part[(size_t)p * NN + idx];
      f32x4 tb = *(const f32x4*)&t_part[(size_t)(3 + p) * NN + idx];
      f32x4 o;
#pragma unroll
      for (int j = 0; j < 4; j++) o[j] = (1.0f / NN) * __builtin_amdgcn_rcpf(ta[j] + tb[j] + EPSC);
      *(f32x4*)&vswz[((c * 4 + q) * 64 + lane) * 4] = o;
    }
  }
  __syncthreads();
  const unsigned char* Kp = K + (size_t)p * NN * NN;
  int r0 = rb * 16;
  const unsigned char* kbase = Kp + (size_t)(r0 + w * 4) * NN + lane * 16;
  float acc0 = 0.f, acc1 = 0.f, acc2 = 0.f, acc3 = 0.f;
#pragma unroll
  for (int c = 0; c < 4; c++) {
    uint4 k0 = *(const uint4*)(kbase + c * 1024);
    uint4 k1 = *(const uint4*)(kbase + (size_t)NN + c * 1024);
    uint4 k2 = *(const uint4*)(kbase + (size_t)2 * NN + c * 1024);
    uint4 k3 = *(const uint4*)(kbase + (size_t)3 * NN + c * 1024);
    f32x4 v0 = *(const f32x4*)&vswz[((c * 4 + 0) * 64 + lane) * 4];
    f32x4 v1 = *(const f32x4*)&vswz[((c * 4 + 1) * 64 + lane) * 4];
    f32x4 v2 = *(const f32x4*)&vswz[((c * 4 + 2) * 64 + lane) * 4];
    f32x4 v3 = *(const f32x4*)&vswz[((c * 4 + 3) * 64 + lane) * 4];
    acc0 += dot16v(k0, v0, v1, v2, v3);
    acc1 += dot16v(k1, v0, v1, v2, v3);
    acc2 += dot16v(k2, v0, v1, v2, v3);
    acc3 += dot16v(k3, v0, v1, v2, v3);
  }
  acc0 = wave_reduce_sum(acc0);
  acc1 = wave_reduce_sum(acc1);
  acc2 = wave_reduce_sum(acc2);
  acc3 = wave_reduce_sum(acc3);
  if (lane == 0) {
    float* ug = u + p * NN + r0 + w * 4;
    ug[0] = (1.0f / NN) / (acc0 + EPSC);
    ug[1] = (1.0f / NN) / (acc1 + EPSC);
    ug[2] = (1.0f / NN) / (acc2 + EPSC);
    ug[3] = (1.0f / NN) / (acc3 + EPSC);
  }
}

// grid dim3(64,2,3), block 256: column pass, NO atomics.
// t_part[(chunk*3+p)*NN + cols] = sum over chunk's 2048 rows of K[row][col]*u[row]
__global__ __launch_bounds__(256) void sink_t(const unsigned char* __restrict__ K,
                                              const float* __restrict__ u, float* __restrict__ t_part) {
  int strip = blockIdx.x;  // 64 cols
  int chunk = blockIdx.y;  // 2048 rows
  int p = blockIdx.z;
  int tid = threadIdx.x, w = tid >> 6, lane = tid & 63;
  int rowlane = lane >> 2, cg = lane & 3;
  const unsigned char* Kp = K + (size_t)p * NN * NN + (size_t)chunk * 2048 * NN + strip * 64 + cg * 16;
  __shared__ float ulds[2048];
  const float* up = u + p * NN + chunk * 2048;
  ((f32x4*)ulds)[tid * 2] = ((const f32x4*)up)[tid * 2];
  ((f32x4*)ulds)[tid * 2 + 1] = ((const f32x4*)up)[tid * 2 + 1];
  __syncthreads();
  float ca[16];
#pragma unroll
  for (int j = 0; j < 16; j++) ca[j] = 0.f;
#pragma unroll 4
  for (int it = 0; it < 32; it++) {
    int r = it * 64 + w * 16 + rowlane;
    uint4 k = *(const uint4*)(Kp + (size_t)r * NN);
    float ur = ulds[r];
    float kd[16];
    fp8x16_decode(k, kd);
#pragma unroll
    for (int j = 0; j < 16; j++) ca[j] += kd[j] * ur;
  }
#pragma unroll
  for (int m = 4; m <= 32; m <<= 1)
#pragma unroll
    for (int j = 0; j < 16; j++) ca[j] += __shfl_xor(ca[j], m, 64);
  __shared__ float red[4][64];
  if (rowlane == 0) {
#pragma unroll
    for (int j = 0; j < 16; j++) red[w][cg * 16 + j] = ca[j];
  }
  __syncthreads();
  if (tid < 64)
    t_part[((size_t)chunk * 3 + p) * NN + strip * 64 + tid] =
        red[0][tid] + red[1][tid] + red[2][tid] + red[3][tid];
}

// grid 768 (p*256+rb), block 256, 16 rows/block: loss += u_i K_ij v_j C_ij, C=-reg*ln(K)
__global__ __launch_bounds__(256) void loss_kernel(const unsigned char* __restrict__ K,
                                                   const float* __restrict__ t_part, const float* __restrict__ u,
                                                   float* __restrict__ out) {
  int bid = blockIdx.x;
  int p = bid >> 8;
  int rb = bid & 255;
  int tid = threadIdx.x;
  int w = tid >> 6, lane = tid & 63;
  __shared__ float vswz[NN];
  {
    int c = tid >> 6;
#pragma unroll
    for (int q = 0; q < 4; q++) {
      int idx = c * 1024 + lane * 16 + q * 4;
      f32x4 ta = *(const f32x4*)&t_part[(size_t)p * NN + idx];
      f32x4 tb = *(const f32x4*)&t_part[(size_t)(3 + p) * NN + idx];
      f32x4 o;
#pragma unroll
      for (int j = 0; j < 4; j++) o[j] = (1.0f / NN) * __builtin_amdgcn_rcpf(ta[j] + tb[j] + EPSC);
      *(f32x4*)&vswz[((c * 4 + q) * 64 + lane) * 4] = o;
    }
  }
  __syncthreads();
  const unsigned char* Kp = K + (size_t)p * NN * NN;
  const float* up = u + p * NN;
  int r0 = rb * 16;
  const unsigned char* kbase = Kp + (size_t)(r0 + w * 4) * NN + lane * 16;
  float acc0 = 0.f, acc1 = 0.f, acc2 = 0.f, acc3 = 0.f;
#pragma unroll
  for (int c = 0; c < 4; c++) {
    uint4 kr[4];
    kr[0] = *(const uint4*)(kbase + c * 1024);
    kr[1] = *(const uint4*)(kbase + (size_t)NN + c * 1024);
    kr[2] = *(const uint4*)(kbase + (size_t)2 * NN + c * 1024);
    kr[3] = *(const uint4*)(kbase + (size_t)3 * NN + c * 1024);
    f32x4 vq[4];
#pragma unroll
    for (int q = 0; q < 4; q++) vq[q] = *(const f32x4*)&vswz[((c * 4 + q) * 64 + lane) * 4];
#pragma unroll
    for (int r = 0; r < 4; r++) {
      float kd[16];
      fp8x16_decode(kr[r], kd);
      float racc = 0.f;
#pragma unroll
      for (int q = 0; q < 4; q++)
#pragma unroll
        for (int j = 0; j < 4; j++) {
          float kf = kd[q * 4 + j];
          racc += kf * vq[q][j] * (-REGC * __logf(kf));
        }
      if (r == 0) acc0 += racc;
      else if (r == 1) acc1 += racc;
      else if (r == 2) acc2 += racc;
      else acc3 += racc;
    }
  }
  float lt = acc0 * up[r0 + w * 4] + acc1 * up[r0 + w * 4 + 1] +
             acc2 * up[r0 + w * 4 + 2] + acc3 * up[r0 + w * 4 + 3];
  lt = wave_reduce_sum(lt);
  __shared__ float red[4];
  if (lane == 0) red[w] = lt;
  __syncthreads();
  if (tid == 0) atomicAdd(out, (red[0] + red[1] + red[2] + red[3]) * (1.0f / 3.0f));
}

extern "C" void kernel_launch(void* const* d_in, const int* in_sizes, int n_in,
                              void* d_out, int out_size, void* d_ws, size_t ws_size,
                              hipStream_t stream) {
  const float* z0 = (const float*)d_in[0];
  const float* z1 = (const float*)d_in[1];
  const float* z2 = (const float*)d_in[2];
  float* out = (float*)d_out;
  char* ws = (char*)d_ws;

  const size_t K_BYTES = (size_t)3 * NN * NN;            // 50331648 (fp8)
  unsigned char* K = (unsigned char*)ws;
  short* zb = (short*)(ws + K_BYTES);                    // 3145728 B
  float* sq = (float*)(ws + K_BYTES + 3145728);          // 49152 B
  float* u = (float*)(ws + K_BYTES + 3145728 + 49152);   // 49152 B
  float* t_part = (float*)(ws + K_BYTES + 3145728 + 2 * 49152);  // 2 chunks x 3 pairs x 4096 f32

  hipMemsetAsync(d_out, 0, sizeof(float), stream);
  hipMemsetAsync(t_part, 0, 2 * 3 * NN * sizeof(float), stream);

  prep_kernel<<<3 * NN, 128, 0, stream>>>(z0, z1, z2, zb, sq);
  kbuild_kernel<<<dim3(32, 32, 3), 256, 0, stream>>>(zb, sq, K, t_part /* chunk0 = K^T*1, chunk1 = 0 */);

  for (int it = 0; it < NSINK; it++) {
    sink_u<<<768, 256, 0, stream>>>(K, t_part, u);
    if (it < NSINK - 1)
      sink_t<<<dim3(64, 2, 3), 256, 0, stream>>>(K, u, t_part);
  }
  // loss recomputes v from the t_part state the LAST sink_u read (we skipped the final sink_t)
  loss_kernel<<<768, 256, 0, stream>>>(K, t_part, u, out);
}

// Round 6
// 446.243 us; speedup vs baseline: 7.8618x; 1.0496x over previous
//
#include <hip/hip_runtime.h>

#define NN 4096
#define DD 128
#define REGC 0.05f
#define EPSC 1e-8f
#define NSINK 10
#define KPAD 144  // shorts; 288B row stride

typedef float f32x4 __attribute__((ext_vector_type(4)));
typedef float f32x2 __attribute__((ext_vector_type(2)));
typedef short s16x8 __attribute__((ext_vector_type(8)));

__device__ __forceinline__ float wave_reduce_sum(float s) {
#pragma unroll
  for (int m = 32; m >= 1; m >>= 1) s += __shfl_xor(s, m, 64);
  return s;
}

__device__ __forceinline__ short f32_to_bf16(float f) {
  union { float f; unsigned u; } x; x.f = f;
  unsigned r = (x.u + 0x7FFFu + ((x.u >> 16) & 1u)) >> 16;
  return (short)r;
}

__device__ __forceinline__ void fp8x4_decode(unsigned int k, float* o) {
  f32x2 lo = __builtin_amdgcn_cvt_pk_f32_fp8((int)k, false);
  f32x2 hi = __builtin_amdgcn_cvt_pk_f32_fp8((int)k, true);
  o[0] = lo[0]; o[1] = lo[1]; o[2] = hi[0]; o[3] = hi[1];
}

__device__ __forceinline__ void fp8x16_decode(uint4 k, float* o) {
  fp8x4_decode(k.x, o); fp8x4_decode(k.y, o + 4);
  fp8x4_decode(k.z, o + 8); fp8x4_decode(k.w, o + 12);
}

__device__ __forceinline__ float dot16v(uint4 k, f32x4 v0, f32x4 v1, f32x4 v2, f32x4 v3) {
  float o[16];
  fp8x16_decode(k, o);
  float s = 0.f;
#pragma unroll
  for (int j = 0; j < 4; j++) s += o[j] * v0[j];
#pragma unroll
  for (int j = 0; j < 4; j++) s += o[4 + j] * v1[j];
#pragma unroll
  for (int j = 0; j < 4; j++) s += o[8 + j] * v2[j];
#pragma unroll
  for (int j = 0; j < 4; j++) s += o[12 + j] * v3[j];
  return s;
}

// dual accumulate: s1 += K*v, s2 += K*v*ln(K)   (loss uses C = -REG*ln K, factored out)
__device__ __forceinline__ void dot16v_dual(uint4 k, f32x4 v0, f32x4 v1, f32x4 v2, f32x4 v3,
                                            float& s1, float& s2) {
  float o[16];
  fp8x16_decode(k, o);
#pragma unroll
  for (int q = 0; q < 4; q++) {
    f32x4 vv = (q == 0) ? v0 : (q == 1) ? v1 : (q == 2) ? v2 : v3;
#pragma unroll
    for (int j = 0; j < 4; j++) {
      float kf = o[q * 4 + j];
      float kv = kf * vv[j];
      s1 += kv;
      s2 += kv * __logf(fmaxf(kf, 1e-6f));
    }
  }
}

// grid 12288 (zi*4096+row), block 128: row norms + bf16 convert
__global__ __launch_bounds__(128) void prep_kernel(const float* __restrict__ z0, const float* __restrict__ z1,
                                                   const float* __restrict__ z2, short* __restrict__ zb,
                                                   float* __restrict__ sq) {
  int row = blockIdx.x;
  int zi = row >> 12;
  const float* z = (zi == 0) ? z0 : ((zi == 1) ? z1 : z2);
  int r = row & (NN - 1);
  float val = z[r * DD + threadIdx.x];
  zb[row * DD + threadIdx.x] = f32_to_bf16(val);
  float s = wave_reduce_sum(val * val);
  __shared__ float red[2];
  if ((threadIdx.x & 63) == 0) red[threadIdx.x >> 6] = s;
  __syncthreads();
  if (threadIdx.x == 0) sq[row] = red[0] + red[1];
}

// grid dim3(32,32,3), block 256: 128x128 tile via LDS-staged MFMA; K=fp8(exp(-C/reg));
// epilogue writes per-block column-sum partials (NO global atomics):
//   cpart[(p*32 + by)*NN + bx*128 + col]
__global__ __launch_bounds__(256) void kbuild_kernel(const short* __restrict__ zb, const float* __restrict__ sq,
                                                     unsigned char* __restrict__ K, float* __restrict__ cpart) {
  int p = blockIdx.z;
  int ai = (p == 2) ? 1 : 0;            // pairs (0,1),(0,2),(1,2)
  int bi = (p == 0) ? 1 : 2;
  const short* xg = zb + ai * NN * DD + blockIdx.y * 128 * DD;
  const short* yg = zb + bi * NN * DD + blockIdx.x * 128 * DD;
  const float* sqx = sq + ai * NN + blockIdx.y * 128;
  const float* sqy = sq + bi * NN + blockIdx.x * 128;
  __shared__ short xs[128 * KPAD];
  __shared__ short ys[128 * KPAD];
  __shared__ float colsum[128];
  int tid = threadIdx.x;
  for (int i = tid; i < 2048; i += 256) {
    int row = i >> 4, seg = i & 15;
    *(uint4*)&xs[row * KPAD + seg * 8] = *(const uint4*)&xg[row * DD + seg * 8];
    *(uint4*)&ys[row * KPAD + seg * 8] = *(const uint4*)&yg[row * DD + seg * 8];
  }
  if (tid < 128) colsum[tid] = 0.f;
  __syncthreads();
  int w = tid >> 6, lane = tid & 63;
  int wr = (w >> 1) * 64, wc = (w & 1) * 64;
  int lrow = lane & 15, lk = lane >> 4;
  f32x4 acc[4][4];
#pragma unroll
  for (int i = 0; i < 4; i++)
#pragma unroll
    for (int j = 0; j < 4; j++) acc[i][j] = (f32x4){0.f, 0.f, 0.f, 0.f};
#pragma unroll
  for (int kk = 0; kk < 4; kk++) {
    s16x8 a[4], b[4];
#pragma unroll
    for (int rt = 0; rt < 4; rt++) {
      a[rt] = *(const s16x8*)&xs[(wr + rt * 16 + lrow) * KPAD + kk * 32 + lk * 8];
      b[rt] = *(const s16x8*)&ys[(wc + rt * 16 + lrow) * KPAD + kk * 32 + lk * 8];
    }
#pragma unroll
    for (int rt = 0; rt < 4; rt++)
#pragma unroll
      for (int ct = 0; ct < 4; ct++)
        acc[rt][ct] = __builtin_amdgcn_mfma_f32_16x16x32_bf16(a[rt], b[ct], acc[rt][ct], 0, 0, 0);
  }
  unsigned char* Kp = K + (size_t)p * NN * NN;
#pragma unroll
  for (int ct = 0; ct < 4; ct++) {
    int coll = wc + ct * 16 + lrow;
    int colg = blockIdx.x * 128 + coll;
    float sy = sqy[coll];
    float cs = 0.f;
#pragma unroll
    for (int rt = 0; rt < 4; rt++) {
#pragma unroll
      for (int r = 0; r < 4; r++) {
        int rowl = wr + rt * 16 + lk * 4 + r;
        float Cv = fmaxf(sqx[rowl] + sy - 2.0f * acc[rt][ct][r], 0.0f);
        float kf = __expf(Cv * (-1.0f / REGC));
        cs += kf;
        int pk = __builtin_amdgcn_cvt_pk_fp8_f32(kf, kf, 0, false);
        Kp[(size_t)(blockIdx.y * 128 + rowl) * NN + colg] = (unsigned char)(pk & 0xFF);
      }
    }
    cs += __shfl_xor(cs, 16, 64);
    cs += __shfl_xor(cs, 32, 64);
    if (lk == 0) atomicAdd(&colsum[coll], cs);  // LDS atomic, cheap
  }
  __syncthreads();
  if (tid < 128)
    cpart[(size_t)(p * 32 + blockIdx.y) * NN + blockIdx.x * 128 + tid] = colsum[tid];
}

// grid dim3(16,3), block 256: v = nu/(sum_by cpart + eps)  (initial v for u0=1)
__global__ __launch_bounds__(256) void vinit_kernel(const float* __restrict__ cpart, float* __restrict__ v) {
  int p = blockIdx.y;
  int col = blockIdx.x * 256 + threadIdx.x;
  float s = 0.f;
#pragma unroll 8
  for (int by = 0; by < 32; by++) s += cpart[(size_t)(p * 32 + by) * NN + col];
  v[p * NN + col] = (1.0f / NN) * __builtin_amdgcn_rcpf(s + EPSC);
}

// grid 768 (p*256+rb), block 256, 16 rows/block. One pass over K per iteration, NO global atomics:
//   A: stage v (precomputed, already reciprocal) into LDS swizzled
//   B: u = mu/(K v + eps) for the block's 16 rows (4 rows/wave, c-order rotated per block+wave)
//   C: per-block t-partial: partial[(p*256+rb)*NN + col] = sum over the 16 rows of K[r][col]*u[r]
__global__ __launch_bounds__(256, 4) void sink_fused(const unsigned char* __restrict__ K,
                                                     const float* __restrict__ v, float* __restrict__ partial) {
  int bid = blockIdx.x;
  int p = bid >> 8;
  int rb = bid & 255;
  int tid = threadIdx.x;
  int w = tid >> 6, lane = tid & 63;
  __shared__ float vswz[NN];   // v[c*1024+lane*16+q*4+j] at [((c*4+q)*64+lane)*4+j]
  __shared__ float ulds[16];
  {
    int c = tid >> 6;
    const float* vp = v + p * NN;
#pragma unroll
    for (int q = 0; q < 4; q++) {
      f32x4 tv = *(const f32x4*)&vp[c * 1024 + lane * 16 + q * 4];
      *(f32x4*)&vswz[((c * 4 + q) * 64 + lane) * 4] = tv;
    }
  }
  __syncthreads();
  const unsigned char* Kp = K + (size_t)p * NN * NN;
  int r0 = rb * 16;
  // phase B: rows r0 + w*4 .. +3, rotated c start (anti-camping)
  {
    const unsigned char* kbase = Kp + (size_t)(r0 + w * 4) * NN + lane * 16;
    float acc0 = 0.f, acc1 = 0.f, acc2 = 0.f, acc3 = 0.f;
    int cc = (rb + w) & 3;
    uint4 ka0 = *(const uint4*)(kbase + cc * 1024);
    uint4 ka1 = *(const uint4*)(kbase + (size_t)NN + cc * 1024);
    uint4 ka2 = *(const uint4*)(kbase + (size_t)2 * NN + cc * 1024);
    uint4 ka3 = *(const uint4*)(kbase + (size_t)3 * NN + cc * 1024);
#pragma unroll
    for (int i = 0; i < 4; i++) {
      int cn = (rb + w + i + 1) & 3;
      uint4 kb0, kb1, kb2, kb3;
      if (i < 3) {
        kb0 = *(const uint4*)(kbase + cn * 1024);
        kb1 = *(const uint4*)(kbase + (size_t)NN + cn * 1024);
        kb2 = *(const uint4*)(kbase + (size_t)2 * NN + cn * 1024);
        kb3 = *(const uint4*)(kbase + (size_t)3 * NN + cn * 1024);
      }
      f32x4 v0 = *(const f32x4*)&vswz[((cc * 4 + 0) * 64 + lane) * 4];
      f32x4 v1 = *(const f32x4*)&vswz[((cc * 4 + 1) * 64 + lane) * 4];
      f32x4 v2 = *(const f32x4*)&vswz[((cc * 4 + 2) * 64 + lane) * 4];
      f32x4 v3 = *(const f32x4*)&vswz[((cc * 4 + 3) * 64 + lane) * 4];
      acc0 += dot16v(ka0, v0, v1, v2, v3);
      acc1 += dot16v(ka1, v0, v1, v2, v3);
      acc2 += dot16v(ka2, v0, v1, v2, v3);
      acc3 += dot16v(ka3, v0, v1, v2, v3);
      ka0 = kb0; ka1 = kb1; ka2 = kb2; ka3 = kb3;
      cc = cn;
    }
    acc0 = wave_reduce_sum(acc0);
    acc1 = wave_reduce_sum(acc1);
    acc2 = wave_reduce_sum(acc2);
    acc3 = wave_reduce_sum(acc3);
    if (lane == 0) {
      ulds[w * 4 + 0] = (1.0f / NN) / (acc0 + EPSC);
      ulds[w * 4 + 1] = (1.0f / NN) / (acc1 + EPSC);
      ulds[w * 4 + 2] = (1.0f / NN) / (acc2 + EPSC);
      ulds[w * 4 + 3] = (1.0f / NN) / (acc3 + EPSC);
    }
  }
  __syncthreads();
  // phase C: thread owns cols tid*16..+15 over the block's 16 rows (L2-warm full-row reads)
  float ca[16];
#pragma unroll
  for (int j = 0; j < 16; j++) ca[j] = 0.f;
  const unsigned char* kc = Kp + (size_t)r0 * NN + tid * 16;
#pragma unroll 4
  for (int r = 0; r < 16; r++) {
    uint4 k = *(const uint4*)(kc + (size_t)r * NN);
    float ur = ulds[r];
    float kd[16];
    fp8x16_decode(k, kd);
#pragma unroll
    for (int j = 0; j < 16; j++) ca[j] += kd[j] * ur;
  }
  float* pd = partial + (size_t)bid * NN + tid * 16;
#pragma unroll
  for (int q = 0; q < 4; q++) *(f32x4*)&pd[q * 4] = (f32x4){ca[q * 4], ca[q * 4 + 1], ca[q * 4 + 2], ca[q * 4 + 3]};
}

// grid dim3(16,3), block 256: v = nu/(sum_b partial + eps)
__global__ __launch_bounds__(256) void vcalc_kernel(const float* __restrict__ partial, float* __restrict__ v) {
  int p = blockIdx.y;
  int col = blockIdx.x * 256 + threadIdx.x;
  const float* pp = partial + (size_t)p * 256 * NN + col;
  float s = 0.f;
#pragma unroll 8
  for (int b = 0; b < 256; b++) s += pp[(size_t)b * NN];
  v[p * NN + col] = (1.0f / NN) * __builtin_amdgcn_rcpf(s + EPSC);
}

// grid 768 (p*256+rb), block 256, 16 rows/block, SINGLE pass:
//   per row: s1 = K·v, s2 = K·v·lnK;  u = mu/(s1+eps);  loss += u*(-REG)*s2... wait C=-REG lnK
//   loss_row = u * (-REG) * s2;  total atomic once per block
__global__ __launch_bounds__(256, 4) void loss_fused(const unsigned char* __restrict__ K,
                                                     const float* __restrict__ v, float* __restrict__ out) {
  int bid = blockIdx.x;
  int p = bid >> 8;
  int rb = bid & 255;
  int tid = threadIdx.x;
  int w = tid >> 6, lane = tid & 63;
  __shared__ float vswz[NN];
  {
    int c = tid >> 6;
    const float* vp = v + p * NN;
#pragma unroll
    for (int q = 0; q < 4; q++) {
      f32x4 tv = *(const f32x4*)&vp[c * 1024 + lane * 16 + q * 4];
      *(f32x4*)&vswz[((c * 4 + q) * 64 + lane) * 4] = tv;
    }
  }
  __syncthreads();
  const unsigned char* Kp = K + (size_t)p * NN * NN;
  int r0 = rb * 16;
  const unsigned char* kbase = Kp + (size_t)(r0 + w * 4) * NN + lane * 16;
  float s1r[4] = {0.f, 0.f, 0.f, 0.f};
  float s2r[4] = {0.f, 0.f, 0.f, 0.f};
  int cc = (rb + w) & 3;
  uint4 ka0 = *(const uint4*)(kbase + cc * 1024);
  uint4 ka1 = *(const uint4*)(kbase + (size_t)NN + cc * 1024);
  uint4 ka2 = *(const uint4*)(kbase + (size_t)2 * NN + cc * 1024);
  uint4 ka3 = *(const uint4*)(kbase + (size_t)3 * NN + cc * 1024);
#pragma unroll
  for (int i = 0; i < 4; i++) {
    int cn = (rb + w + i + 1) & 3;
    uint4 kb0, kb1, kb2, kb3;
    if (i < 3) {
      kb0 = *(const uint4*)(kbase + cn * 1024);
      kb1 = *(const uint4*)(kbase + (size_t)NN + cn * 1024);
      kb2 = *(const uint4*)(kbase + (size_t)2 * NN + cn * 1024);
      kb3 = *(const uint4*)(kbase + (size_t)3 * NN + cn * 1024);
    }
    f32x4 v0 = *(const f32x4*)&vswz[((cc * 4 + 0) * 64 + lane) * 4];
    f32x4 v1 = *(const f32x4*)&vswz[((cc * 4 + 1) * 64 + lane) * 4];
    f32x4 v2 = *(const f32x4*)&vswz[((cc * 4 + 2) * 64 + lane) * 4];
    f32x4 v3 = *(const f32x4*)&vswz[((cc * 4 + 3) * 64 + lane) * 4];
    dot16v_dual(ka0, v0, v1, v2, v3, s1r[0], s2r[0]);
    dot16v_dual(ka1, v0, v1, v2, v3, s1r[1], s2r[1]);
    dot16v_dual(ka2, v0, v1, v2, v3, s1r[2], s2r[2]);
    dot16v_dual(ka3, v0, v1, v2, v3, s1r[3], s2r[3]);
    ka0 = kb0; ka1 = kb1; ka2 = kb2; ka3 = kb3;
    cc = cn;
  }
  float lt = 0.f;
#pragma unroll
  for (int r = 0; r < 4; r++) {
    float s1 = wave_reduce_sum(s1r[r]);
    float s2 = wave_reduce_sum(s2r[r]);
    float u = (1.0f / NN) / (s1 + EPSC);
    lt += u * (-REGC) * s2;
  }
  __shared__ float red[4];
  if (lane == 0) red[w] = lt;
  __syncthreads();
  if (tid == 0) atomicAdd(out, (red[0] + red[1] + red[2] + red[3]) * (1.0f / 3.0f));
}

extern "C" void kernel_launch(void* const* d_in, const int* in_sizes, int n_in,
                              void* d_out, int out_size, void* d_ws, size_t ws_size,
                              hipStream_t stream) {
  const float* z0 = (const float*)d_in[0];
  const float* z1 = (const float*)d_in[1];
  const float* z2 = (const float*)d_in[2];
  float* out = (float*)d_out;
  char* ws = (char*)d_ws;

  const size_t K_BYTES = (size_t)3 * NN * NN;            // 50331648 (fp8)
  unsigned char* K = (unsigned char*)ws;
  short* zb = (short*)(ws + K_BYTES);                    // 3145728 B
  float* sq = (float*)(ws + K_BYTES + 3145728);          // 49152 B
  float* v = (float*)(ws + K_BYTES + 3145728 + 49152);   // 49152 B
  float* cpart = (float*)(ws + K_BYTES + 3145728 + 2 * 49152);   // 3*32*4096*4 = 1572864 B
  float* partial = (float*)(ws + K_BYTES + 3145728 + 2 * 49152 + 1572864);  // 3*256*4096*4 = 12.6 MB

  hipMemsetAsync(d_out, 0, sizeof(float), stream);

  prep_kernel<<<3 * NN, 128, 0, stream>>>(z0, z1, z2, zb, sq);
  kbuild_kernel<<<dim3(32, 32, 3), 256, 0, stream>>>(zb, sq, K, cpart);
  vinit_kernel<<<dim3(16, 3), 256, 0, stream>>>(cpart, v);

  for (int it = 0; it < NSINK; it++) {
    sink_fused<<<768, 256, 0, stream>>>(K, v, partial);
    vcalc_kernel<<<dim3(16, 3), 256, 0, stream>>>(partial, v);
  }
  loss_fused<<<768, 256, 0, stream>>>(K, v, out);
}

// Round 7
// 364.221 us; speedup vs baseline: 9.6322x; 1.2252x over previous
//
#include <hip/hip_runtime.h>

#define NN 4096
#define DD 128
#define REGC 0.05f
#define EPSC 1e-8f
#define NSINK 8
#define KPAD 144  // shorts; 288B row stride

typedef float f32x4 __attribute__((ext_vector_type(4)));
typedef float f32x2 __attribute__((ext_vector_type(2)));
typedef short s16x8 __attribute__((ext_vector_type(8)));

__device__ __forceinline__ float wave_reduce_sum(float s) {
#pragma unroll
  for (int m = 32; m >= 1; m >>= 1) s += __shfl_xor(s, m, 64);
  return s;
}

__device__ __forceinline__ short f32_to_bf16(float f) {
  union { float f; unsigned u; } x; x.f = f;
  unsigned r = (x.u + 0x7FFFu + ((x.u >> 16) & 1u)) >> 16;
  return (short)r;
}

__device__ __forceinline__ void fp8x4_decode(unsigned int k, float* o) {
  f32x2 lo = __builtin_amdgcn_cvt_pk_f32_fp8((int)k, false);
  f32x2 hi = __builtin_amdgcn_cvt_pk_f32_fp8((int)k, true);
  o[0] = lo[0]; o[1] = lo[1]; o[2] = hi[0]; o[3] = hi[1];
}

__device__ __forceinline__ void fp8x8_decode(uint2 k, float* o) {
  fp8x4_decode(k.x, o); fp8x4_decode(k.y, o + 4);
}

__device__ __forceinline__ void fp8x16_decode(uint4 k, float* o) {
  fp8x4_decode(k.x, o); fp8x4_decode(k.y, o + 4);
  fp8x4_decode(k.z, o + 8); fp8x4_decode(k.w, o + 12);
}

__device__ __forceinline__ float dot16v(uint4 k, f32x4 v0, f32x4 v1, f32x4 v2, f32x4 v3) {
  float o[16];
  fp8x16_decode(k, o);
  float s = 0.f;
#pragma unroll
  for (int j = 0; j < 4; j++) s += o[j] * v0[j];
#pragma unroll
  for (int j = 0; j < 4; j++) s += o[4 + j] * v1[j];
#pragma unroll
  for (int j = 0; j < 4; j++) s += o[8 + j] * v2[j];
#pragma unroll
  for (int j = 0; j < 4; j++) s += o[12 + j] * v3[j];
  return s;
}

// dual accumulate: s1 += K*v, s2 += K*v*ln(K)   (loss uses C = -REG*ln K, factored out)
__device__ __forceinline__ void dot16v_dual(uint4 k, f32x4 v0, f32x4 v1, f32x4 v2, f32x4 v3,
                                            float& s1, float& s2) {
  float o[16];
  fp8x16_decode(k, o);
#pragma unroll
  for (int q = 0; q < 4; q++) {
    f32x4 vv = (q == 0) ? v0 : (q == 1) ? v1 : (q == 2) ? v2 : v3;
#pragma unroll
    for (int j = 0; j < 4; j++) {
      float kf = o[q * 4 + j];
      float kv = kf * vv[j];
      s1 += kv;
      s2 += kv * __logf(fmaxf(kf, 1e-6f));
    }
  }
}

// grid 12288 (zi*4096+row), block 128: row norms + bf16 convert
__global__ __launch_bounds__(128) void prep_kernel(const float* __restrict__ z0, const float* __restrict__ z1,
                                                   const float* __restrict__ z2, short* __restrict__ zb,
                                                   float* __restrict__ sq) {
  int row = blockIdx.x;
  int zi = row >> 12;
  const float* z = (zi == 0) ? z0 : ((zi == 1) ? z1 : z2);
  int r = row & (NN - 1);
  float val = z[r * DD + threadIdx.x];
  zb[row * DD + threadIdx.x] = f32_to_bf16(val);
  float s = wave_reduce_sum(val * val);
  __shared__ float red[2];
  if ((threadIdx.x & 63) == 0) red[threadIdx.x >> 6] = s;
  __syncthreads();
  if (threadIdx.x == 0) sq[row] = red[0] + red[1];
}

// grid dim3(32,32,3), block 256: 128x128 tile via LDS-staged MFMA; K=fp8(exp(-C/reg));
// epilogue writes per-block column-sum partials: cpart[(p*32 + by)*NN + bx*128 + col]
__global__ __launch_bounds__(256) void kbuild_kernel(const short* __restrict__ zb, const float* __restrict__ sq,
                                                     unsigned char* __restrict__ K, float* __restrict__ cpart) {
  int p = blockIdx.z;
  int ai = (p == 2) ? 1 : 0;            // pairs (0,1),(0,2),(1,2)
  int bi = (p == 0) ? 1 : 2;
  const short* xg = zb + ai * NN * DD + blockIdx.y * 128 * DD;
  const short* yg = zb + bi * NN * DD + blockIdx.x * 128 * DD;
  const float* sqx = sq + ai * NN + blockIdx.y * 128;
  const float* sqy = sq + bi * NN + blockIdx.x * 128;
  __shared__ short xs[128 * KPAD];
  __shared__ short ys[128 * KPAD];
  __shared__ float colsum[128];
  int tid = threadIdx.x;
  for (int i = tid; i < 2048; i += 256) {
    int row = i >> 4, seg = i & 15;
    *(uint4*)&xs[row * KPAD + seg * 8] = *(const uint4*)&xg[row * DD + seg * 8];
    *(uint4*)&ys[row * KPAD + seg * 8] = *(const uint4*)&yg[row * DD + seg * 8];
  }
  if (tid < 128) colsum[tid] = 0.f;
  __syncthreads();
  int w = tid >> 6, lane = tid & 63;
  int wr = (w >> 1) * 64, wc = (w & 1) * 64;
  int lrow = lane & 15, lk = lane >> 4;
  f32x4 acc[4][4];
#pragma unroll
  for (int i = 0; i < 4; i++)
#pragma unroll
    for (int j = 0; j < 4; j++) acc[i][j] = (f32x4){0.f, 0.f, 0.f, 0.f};
#pragma unroll
  for (int kk = 0; kk < 4; kk++) {
    s16x8 a[4], b[4];
#pragma unroll
    for (int rt = 0; rt < 4; rt++) {
      a[rt] = *(const s16x8*)&xs[(wr + rt * 16 + lrow) * KPAD + kk * 32 + lk * 8];
      b[rt] = *(const s16x8*)&ys[(wc + rt * 16 + lrow) * KPAD + kk * 32 + lk * 8];
    }
#pragma unroll
    for (int rt = 0; rt < 4; rt++)
#pragma unroll
      for (int ct = 0; ct < 4; ct++)
        acc[rt][ct] = __builtin_amdgcn_mfma_f32_16x16x32_bf16(a[rt], b[ct], acc[rt][ct], 0, 0, 0);
  }
  unsigned char* Kp = K + (size_t)p * NN * NN;
#pragma unroll
  for (int ct = 0; ct < 4; ct++) {
    int coll = wc + ct * 16 + lrow;
    int colg = blockIdx.x * 128 + coll;
    float sy = sqy[coll];
    float cs = 0.f;
#pragma unroll
    for (int rt = 0; rt < 4; rt++) {
#pragma unroll
      for (int r = 0; r < 4; r++) {
        int rowl = wr + rt * 16 + lk * 4 + r;
        float Cv = fmaxf(sqx[rowl] + sy - 2.0f * acc[rt][ct][r], 0.0f);
        float kf = __expf(Cv * (-1.0f / REGC));
        cs += kf;
        int pk = __builtin_amdgcn_cvt_pk_fp8_f32(kf, kf, 0, false);
        Kp[(size_t)(blockIdx.y * 128 + rowl) * NN + colg] = (unsigned char)(pk & 0xFF);
      }
    }
    cs += __shfl_xor(cs, 16, 64);
    cs += __shfl_xor(cs, 32, 64);
    if (lk == 0) atomicAdd(&colsum[coll], cs);  // LDS atomic, cheap
  }
  __syncthreads();
  if (tid < 128)
    cpart[(size_t)(p * 32 + blockIdx.y) * NN + blockIdx.x * 128 + tid] = colsum[tid];
}

// grid dim3(16,3), block 256: v = nu/(sum_by cpart + eps)  (initial v for u0=1)
__global__ __launch_bounds__(256) void vinit_kernel(const float* __restrict__ cpart, float* __restrict__ v) {
  int p = blockIdx.y;
  int col = blockIdx.x * 256 + threadIdx.x;
  float s = 0.f;
#pragma unroll 8
  for (int by = 0; by < 32; by++) s += cpart[(size_t)(p * 32 + by) * NN + col];
  v[p * NN + col] = (1.0f / NN) * __builtin_amdgcn_rcpf(s + EPSC);
}

// grid 768 (p*256+rb), block 512 (8 waves), 16 rows/block, 2 rows/wave.
//   A: stage v (already reciprocal) into LDS swizzled
//   B: u = mu/(K v + eps), depth-2 c-chunk prefetch, rotated start (anti-camping)
//   C: partial[(p*256+rb)*NN + col] = sum over 16 rows of K[r][col]*u[r]  (L2-warm)
__global__ __launch_bounds__(512, 6) void sink_fused(const unsigned char* __restrict__ K,
                                                     const float* __restrict__ v, float* __restrict__ partial) {
  int bid = blockIdx.x;
  int p = bid >> 8;
  int rb = bid & 255;
  int tid = threadIdx.x;
  int w = tid >> 6, lane = tid & 63;
  __shared__ float vswz[NN];   // v[c*1024+l6*16+q*4+j] at [((c*4+q)*64+l6)*4+j]
  __shared__ float ulds[16];
  {
    const float* vp = v + p * NN;
#pragma unroll
    for (int bb = 0; bb < 2; bb++) {
      int b = tid + bb * 512;
      int l6 = b & 63, cq = b >> 6;
      int col = (cq >> 2) * 1024 + l6 * 16 + (cq & 3) * 4;
      *(f32x4*)&vswz[b * 4] = *(const f32x4*)&vp[col];
    }
  }
  __syncthreads();
  const unsigned char* Kp = K + (size_t)p * NN * NN;
  int r0 = rb * 16;
  // phase B
  {
    const unsigned char* kr0 = Kp + (size_t)(r0 + w * 2) * NN + lane * 16;
    const unsigned char* kr1 = kr0 + NN;
    int s = (rb + w) & 3;
    uint4 ka[4], kb[4];
    ka[0] = *(const uint4*)(kr0 + ((s + 0) & 3) * 1024);
    kb[0] = *(const uint4*)(kr1 + ((s + 0) & 3) * 1024);
    ka[1] = *(const uint4*)(kr0 + ((s + 1) & 3) * 1024);
    kb[1] = *(const uint4*)(kr1 + ((s + 1) & 3) * 1024);
    float acc0 = 0.f, acc1 = 0.f;
#pragma unroll
    for (int i = 0; i < 4; i++) {
      int cc = (s + i) & 3;
      if (i < 2) {
        int cn = (s + i + 2) & 3;
        ka[i + 2] = *(const uint4*)(kr0 + cn * 1024);
        kb[i + 2] = *(const uint4*)(kr1 + cn * 1024);
      }
      f32x4 v0 = *(const f32x4*)&vswz[((cc * 4 + 0) * 64 + lane) * 4];
      f32x4 v1 = *(const f32x4*)&vswz[((cc * 4 + 1) * 64 + lane) * 4];
      f32x4 v2 = *(const f32x4*)&vswz[((cc * 4 + 2) * 64 + lane) * 4];
      f32x4 v3 = *(const f32x4*)&vswz[((cc * 4 + 3) * 64 + lane) * 4];
      acc0 += dot16v(ka[i], v0, v1, v2, v3);
      acc1 += dot16v(kb[i], v0, v1, v2, v3);
    }
    acc0 = wave_reduce_sum(acc0);
    acc1 = wave_reduce_sum(acc1);
    if (lane == 0) {
      ulds[w * 2 + 0] = (1.0f / NN) / (acc0 + EPSC);
      ulds[w * 2 + 1] = (1.0f / NN) / (acc1 + EPSC);
    }
  }
  __syncthreads();
  // phase C: thread owns cols tid*8..+7 over the block's 16 rows
  float ca[8];
#pragma unroll
  for (int j = 0; j < 8; j++) ca[j] = 0.f;
  const unsigned char* kc = Kp + (size_t)r0 * NN + tid * 8;
#pragma unroll 4
  for (int r = 0; r < 16; r++) {
    uint2 k = *(const uint2*)(kc + (size_t)r * NN);
    float kd[8];
    fp8x8_decode(k, kd);
    float ur = ulds[r];
#pragma unroll
    for (int j = 0; j < 8; j++) ca[j] += kd[j] * ur;
  }
  float* pd = partial + (size_t)bid * NN + tid * 8;
  *(f32x4*)&pd[0] = (f32x4){ca[0], ca[1], ca[2], ca[3]};
  *(f32x4*)&pd[4] = (f32x4){ca[4], ca[5], ca[6], ca[7]};
}

// grid dim3(16,3), block 256: v = nu/(sum_b partial + eps)
__global__ __launch_bounds__(256) void vcalc_kernel(const float* __restrict__ partial, float* __restrict__ v) {
  int p = blockIdx.y;
  int col = blockIdx.x * 256 + threadIdx.x;
  const float* pp = partial + (size_t)p * 256 * NN + col;
  float s = 0.f;
#pragma unroll 8
  for (int b = 0; b < 256; b++) s += pp[(size_t)b * NN];
  v[p * NN + col] = (1.0f / NN) * __builtin_amdgcn_rcpf(s + EPSC);
}

// grid 768 (p*256+rb), block 512, 16 rows/block, 2 rows/wave, single pass:
//   s1 = K·v, s2 = K·v·lnK per row; u = mu/(s1+eps); loss_row = u*(-REG)*s2
__global__ __launch_bounds__(512, 6) void loss_fused(const unsigned char* __restrict__ K,
                                                     const float* __restrict__ v, float* __restrict__ out) {
  int bid = blockIdx.x;
  int p = bid >> 8;
  int rb = bid & 255;
  int tid = threadIdx.x;
  int w = tid >> 6, lane = tid & 63;
  __shared__ float vswz[NN];
  {
    const float* vp = v + p * NN;
#pragma unroll
    for (int bb = 0; bb < 2; bb++) {
      int b = tid + bb * 512;
      int l6 = b & 63, cq = b >> 6;
      int col = (cq >> 2) * 1024 + l6 * 16 + (cq & 3) * 4;
      *(f32x4*)&vswz[b * 4] = *(const f32x4*)&vp[col];
    }
  }
  __syncthreads();
  const unsigned char* Kp = K + (size_t)p * NN * NN;
  int r0 = rb * 16;
  const unsigned char* kr0 = Kp + (size_t)(r0 + w * 2) * NN + lane * 16;
  const unsigned char* kr1 = kr0 + NN;
  int s = (rb + w) & 3;
  uint4 ka[4], kb[4];
  ka[0] = *(const uint4*)(kr0 + ((s + 0) & 3) * 1024);
  kb[0] = *(const uint4*)(kr1 + ((s + 0) & 3) * 1024);
  ka[1] = *(const uint4*)(kr0 + ((s + 1) & 3) * 1024);
  kb[1] = *(const uint4*)(kr1 + ((s + 1) & 3) * 1024);
  float s1a = 0.f, s2a = 0.f, s1b = 0.f, s2b = 0.f;
#pragma unroll
  for (int i = 0; i < 4; i++) {
    int cc = (s + i) & 3;
    if (i < 2) {
      int cn = (s + i + 2) & 3;
      ka[i + 2] = *(const uint4*)(kr0 + cn * 1024);
      kb[i + 2] = *(const uint4*)(kr1 + cn * 1024);
    }
    f32x4 v0 = *(const f32x4*)&vswz[((cc * 4 + 0) * 64 + lane) * 4];
    f32x4 v1 = *(const f32x4*)&vswz[((cc * 4 + 1) * 64 + lane) * 4];
    f32x4 v2 = *(const f32x4*)&vswz[((cc * 4 + 2) * 64 + lane) * 4];
    f32x4 v3 = *(const f32x4*)&vswz[((cc * 4 + 3) * 64 + lane) * 4];
    dot16v_dual(ka[i], v0, v1, v2, v3, s1a, s2a);
    dot16v_dual(kb[i], v0, v1, v2, v3, s1b, s2b);
  }
  s1a = wave_reduce_sum(s1a);
  s2a = wave_reduce_sum(s2a);
  s1b = wave_reduce_sum(s1b);
  s2b = wave_reduce_sum(s2b);
  float ua = (1.0f / NN) / (s1a + EPSC);
  float ub = (1.0f / NN) / (s1b + EPSC);
  float lt = ua * (-REGC) * s2a + ub * (-REGC) * s2b;
  __shared__ float red[8];
  if (lane == 0) red[w] = lt;
  __syncthreads();
  if (tid == 0) {
    float t = 0.f;
#pragma unroll
    for (int i = 0; i < 8; i++) t += red[i];
    atomicAdd(out, t * (1.0f / 3.0f));
  }
}

extern "C" void kernel_launch(void* const* d_in, const int* in_sizes, int n_in,
                              void* d_out, int out_size, void* d_ws, size_t ws_size,
                              hipStream_t stream) {
  const float* z0 = (const float*)d_in[0];
  const float* z1 = (const float*)d_in[1];
  const float* z2 = (const float*)d_in[2];
  float* out = (float*)d_out;
  char* ws = (char*)d_ws;

  const size_t K_BYTES = (size_t)3 * NN * NN;            // 50331648 (fp8)
  unsigned char* K = (unsigned char*)ws;
  short* zb = (short*)(ws + K_BYTES);                    // 3145728 B
  float* sq = (float*)(ws + K_BYTES + 3145728);          // 49152 B
  float* v = (float*)(ws + K_BYTES + 3145728 + 49152);   // 49152 B
  float* cpart = (float*)(ws + K_BYTES + 3145728 + 2 * 49152);   // 1572864 B
  float* partial = (float*)(ws + K_BYTES + 3145728 + 2 * 49152 + 1572864);  // 12.6 MB

  hipMemsetAsync(d_out, 0, sizeof(float), stream);

  prep_kernel<<<3 * NN, 128, 0, stream>>>(z0, z1, z2, zb, sq);
  kbuild_kernel<<<dim3(32, 32, 3), 256, 0, stream>>>(zb, sq, K, cpart);
  vinit_kernel<<<dim3(16, 3), 256, 0, stream>>>(cpart, v);

  for (int it = 0; it < NSINK; it++) {
    sink_fused<<<768, 512, 0, stream>>>(K, v, partial);
    vcalc_kernel<<<dim3(16, 3), 256, 0, stream>>>(partial, v);
  }
  loss_fused<<<768, 512, 0, stream>>>(K, v, out);
}

// Round 8
// 336.713 us; speedup vs baseline: 10.4192x; 1.0817x over previous
//
#include <hip/hip_runtime.h>

#define NN 4096
#define DD 128
#define REGC 0.05f
#define EPSC 1e-8f
#define NSINK 6
#define KPAD2 136   // shorts; 272B row stride, keeps 16B row alignment

typedef float f32x4 __attribute__((ext_vector_type(4)));
typedef float f32x2 __attribute__((ext_vector_type(2)));
typedef short s16x8 __attribute__((ext_vector_type(8)));

__device__ __forceinline__ float wave_reduce_sum(float s) {
#pragma unroll
  for (int m = 32; m >= 1; m >>= 1) s += __shfl_xor(s, m, 64);
  return s;
}

__device__ __forceinline__ short f32_to_bf16(float f) {
  union { float f; unsigned u; } x; x.f = f;
  unsigned r = (x.u + 0x7FFFu + ((x.u >> 16) & 1u)) >> 16;
  return (short)r;
}

__device__ __forceinline__ void fp8x4_decode(unsigned int k, float* o) {
  f32x2 lo = __builtin_amdgcn_cvt_pk_f32_fp8((int)k, false);
  f32x2 hi = __builtin_amdgcn_cvt_pk_f32_fp8((int)k, true);
  o[0] = lo[0]; o[1] = lo[1]; o[2] = hi[0]; o[3] = hi[1];
}

__device__ __forceinline__ void fp8x16_decode(uint4 k, float* o) {
  fp8x4_decode(k.x, o); fp8x4_decode(k.y, o + 4);
  fp8x4_decode(k.z, o + 8); fp8x4_decode(k.w, o + 12);
}

__device__ __forceinline__ float dot16v(uint4 k, f32x4 v0, f32x4 v1, f32x4 v2, f32x4 v3) {
  float o[16];
  fp8x16_decode(k, o);
  float s = 0.f;
#pragma unroll
  for (int j = 0; j < 4; j++) s += o[j] * v0[j];
#pragma unroll
  for (int j = 0; j < 4; j++) s += o[4 + j] * v1[j];
#pragma unroll
  for (int j = 0; j < 4; j++) s += o[8 + j] * v2[j];
#pragma unroll
  for (int j = 0; j < 4; j++) s += o[12 + j] * v3[j];
  return s;
}

// dual accumulate: s1 += K*v, s2 += K*v*ln(K)   (loss C = -REG*lnK factored out)
__device__ __forceinline__ void dot16v_dual(uint4 k, f32x4 v0, f32x4 v1, f32x4 v2, f32x4 v3,
                                            float& s1, float& s2) {
  float o[16];
  fp8x16_decode(k, o);
#pragma unroll
  for (int q = 0; q < 4; q++) {
    f32x4 vv = (q == 0) ? v0 : (q == 1) ? v1 : (q == 2) ? v2 : v3;
#pragma unroll
    for (int j = 0; j < 4; j++) {
      float kf = o[q * 4 + j];
      float kv = kf * vv[j];
      s1 += kv;
      s2 += kv * __logf(fmaxf(kf, 1e-6f));
    }
  }
}

// async global->LDS, 16B per lane; LDS slot = uniform base + lane*16
__device__ __forceinline__ void async_ld16(const unsigned char* g, unsigned char* l) {
  __builtin_amdgcn_global_load_lds((const __attribute__((address_space(1))) void*)g,
                                   (__attribute__((address_space(3))) void*)l, 16, 0, 0);
}

// grid 12288 (zi*4096+row), block 128: row norms + bf16 convert
__global__ __launch_bounds__(128) void prep_kernel(const float* __restrict__ z0, const float* __restrict__ z1,
                                                   const float* __restrict__ z2, short* __restrict__ zb,
                                                   float* __restrict__ sq) {
  int row = blockIdx.x;
  int zi = row >> 12;
  const float* z = (zi == 0) ? z0 : ((zi == 1) ? z1 : z2);
  int r = row & (NN - 1);
  float val = z[r * DD + threadIdx.x];
  zb[row * DD + threadIdx.x] = f32_to_bf16(val);
  float s = wave_reduce_sum(val * val);
  __shared__ float red[2];
  if ((threadIdx.x & 63) == 0) red[threadIdx.x >> 6] = s;
  __syncthreads();
  if (threadIdx.x == 0) sq[row] = red[0] + red[1];
}

// grid dim3(32,32,3), block 256. K rows = x (pair ai, tiled by blockIdx.y),
// K cols = y (pair bi, tiled by blockIdx.x). A operand = y (LDS), B operand = x (global),
// so lane's 4 acc regs are HORIZONTAL in K -> pack u32 -> padded LDS tile -> full-line stores.
// Also per-block column sums -> cpart[(p*32+by)*NN + bx*128 + col].
__global__ __launch_bounds__(256, 3) void kbuild_kernel(const short* __restrict__ zb, const float* __restrict__ sq,
                                                        unsigned char* __restrict__ K, float* __restrict__ cpart) {
  int p = blockIdx.z;
  int ai = (p == 2) ? 1 : 0;            // pairs (0,1),(0,2),(1,2)
  int bi = (p == 0) ? 1 : 2;
  const short* xg = zb + ai * NN * DD + blockIdx.y * 128 * DD;   // B operand (K rows)
  const short* yg = zb + bi * NN * DD + blockIdx.x * 128 * DD;   // A operand (K cols), staged
  const float* sqx = sq + ai * NN + blockIdx.y * 128;
  const float* sqy = sq + bi * NN + blockIdx.x * 128;
  __shared__ __align__(16) unsigned char smem[128 * KPAD2 * 2];  // ys (34816B), later aliased by kt (18432B)
  __shared__ float colsum[128];
  short* ys = (short*)smem;
  unsigned int* kt = (unsigned int*)smem;   // [128][36] u32, row stride 144B
  int tid = threadIdx.x;
  for (int i = tid; i < 2048; i += 256) {
    int row = i >> 4, seg = i & 15;
    *(uint4*)&ys[row * KPAD2 + seg * 8] = *(const uint4*)&yg[row * DD + seg * 8];
  }
  if (tid < 128) colsum[tid] = 0.f;
  __syncthreads();
  int w = tid >> 6, lane = tid & 63;
  int wy = (w >> 1) * 64, wx = (w & 1) * 64;   // y(col) / x(row) quadrants
  int lrow = lane & 15, lk = lane >> 4;
  f32x4 acc[4][4];   // [yt][xt]
#pragma unroll
  for (int i = 0; i < 4; i++)
#pragma unroll
    for (int j = 0; j < 4; j++) acc[i][j] = (f32x4){0.f, 0.f, 0.f, 0.f};
#pragma unroll
  for (int kk = 0; kk < 4; kk++) {
    s16x8 a[4], b[4];
#pragma unroll
    for (int t = 0; t < 4; t++) {
      a[t] = *(const s16x8*)&ys[(wy + t * 16 + lrow) * KPAD2 + kk * 32 + lk * 8];
      b[t] = *(const s16x8*)&xg[(wx + t * 16 + lrow) * DD + kk * 32 + lk * 8];
    }
#pragma unroll
    for (int yt = 0; yt < 4; yt++)
#pragma unroll
      for (int xt = 0; xt < 4; xt++)
        acc[yt][xt] = __builtin_amdgcn_mfma_f32_16x16x32_bf16(a[yt], b[xt], acc[yt][xt], 0, 0, 0);
  }
  // D layout: lane&15 -> B-dim (x, K-row); (lane>>4)*4+reg -> A-dim (y, K-col).
  unsigned int pk[4][4];   // [xt][yt] packed 4 consecutive K-cols
  float csum[4][4];        // [yt][r] column-sum partials
#pragma unroll
  for (int i = 0; i < 4; i++)
#pragma unroll
    for (int j = 0; j < 4; j++) csum[i][j] = 0.f;
#pragma unroll
  for (int xt = 0; xt < 4; xt++) {
    int xl = wx + xt * 16 + lrow;
    float sx = sqx[xl];
#pragma unroll
    for (int yt = 0; yt < 4; yt++) {
      int yl0 = wy + yt * 16 + lk * 4;
      float kf[4];
#pragma unroll
      for (int r = 0; r < 4; r++) {
        float Cv = fmaxf(sx + sqy[yl0 + r] - 2.0f * acc[yt][xt][r], 0.0f);
        kf[r] = __expf(Cv * (-1.0f / REGC));
        csum[yt][r] += kf[r];
      }
      int pw = __builtin_amdgcn_cvt_pk_fp8_f32(kf[0], kf[1], 0, false);
      pw = __builtin_amdgcn_cvt_pk_fp8_f32(kf[2], kf[3], pw, true);
      pk[xt][yt] = (unsigned int)pw;
    }
  }
  // column sums: reduce across the 16 lrow lanes, accumulate across x-quadrant waves via LDS atomics
#pragma unroll
  for (int yt = 0; yt < 4; yt++)
#pragma unroll
    for (int r = 0; r < 4; r++) {
      float s = csum[yt][r];
      s += __shfl_xor(s, 1, 64); s += __shfl_xor(s, 2, 64);
      s += __shfl_xor(s, 4, 64); s += __shfl_xor(s, 8, 64);
      if (lrow == 0) atomicAdd(&colsum[wy + yt * 16 + lk * 4 + r], s);
    }
  __syncthreads();   // everyone done reading ys; safe to alias with kt
#pragma unroll
  for (int xt = 0; xt < 4; xt++) {
    int xl = wx + xt * 16 + lrow;
#pragma unroll
    for (int yt = 0; yt < 4; yt++)
      kt[xl * 36 + ((wy + yt * 16) >> 2) + lk] = pk[xt][yt];
  }
  __syncthreads();
  // coalesced store: thread -> (row = tid>>3 (+32/round), 16B chunk = tid&7); full 64B lines
  unsigned char* Kb = K + (size_t)p * NN * NN + (size_t)blockIdx.y * 128 * NN + blockIdx.x * 128;
#pragma unroll
  for (int rd = 0; rd < 4; rd++) {
    int rl = (tid >> 3) + rd * 32;
    int ch = tid & 7;
    uint4 d = *(const uint4*)&kt[rl * 36 + ch * 4];
    *(uint4*)(Kb + (size_t)rl * NN + ch * 16) = d;
  }
  if (tid < 128)
    cpart[(size_t)(p * 32 + blockIdx.y) * NN + blockIdx.x * 128 + tid] = colsum[tid];
}

// grid dim3(16,3), block 256: v = nu/(sum_by cpart + eps)  (initial v for u0=1)
__global__ __launch_bounds__(256) void vinit_kernel(const float* __restrict__ cpart, float* __restrict__ v) {
  int p = blockIdx.y;
  int col = blockIdx.x * 256 + threadIdx.x;
  float s = 0.f;
#pragma unroll 8
  for (int by = 0; by < 32; by++) s += cpart[(size_t)(p * 32 + by) * NN + col];
  v[p * NN + col] = (1.0f / NN) * __builtin_amdgcn_rcpf(s + EPSC);
}

// grid 1536 (p*512+rb), block 256 (4 waves), 8 rows/block:
//   A: async-DMA the block's 8 K rows (32 KB) into LDS
//   B: wave w: rows 2w,2w+1: u = mu/(K v + eps); v read from global (L1/L2-hot)
//   C: thread owns 16 cols over 8 rows (from LDS) -> partial[(p*512+rb)*NN + col]
__global__ __launch_bounds__(256, 3) void sink_fused(const unsigned char* __restrict__ K,
                                                     const float* __restrict__ v, float* __restrict__ partial) {
  int bid = blockIdx.x;
  int p = bid >> 9;
  int rb = bid & 511;
  int tid = threadIdx.x, w = tid >> 6, lane = tid & 63;
  __shared__ __align__(16) unsigned char ks[8 * NN];
  __shared__ float ulds[8];
  const unsigned char* Kp = K + (size_t)p * NN * NN;
  int r0 = rb * 8;
  {
    const unsigned char* g = Kp + (size_t)r0 * NN + w * 8192 + lane * 16;
#pragma unroll
    for (int i = 0; i < 8; i++)
      async_ld16(g + i * 1024, &ks[w * 8192 + i * 1024]);
  }
  __syncthreads();
  const float* vp = v + p * NN;
  {
    float acc0 = 0.f, acc1 = 0.f;
#pragma unroll
    for (int c = 0; c < 4; c++) {
      uint4 k0 = *(const uint4*)&ks[(2 * w) * NN + c * 1024 + lane * 16];
      uint4 k1 = *(const uint4*)&ks[(2 * w + 1) * NN + c * 1024 + lane * 16];
      const float* vb = vp + c * 1024 + lane * 16;
      f32x4 v0 = *(const f32x4*)(vb + 0);
      f32x4 v1 = *(const f32x4*)(vb + 4);
      f32x4 v2 = *(const f32x4*)(vb + 8);
      f32x4 v3 = *(const f32x4*)(vb + 12);
      acc0 += dot16v(k0, v0, v1, v2, v3);
      acc1 += dot16v(k1, v0, v1, v2, v3);
    }
    acc0 = wave_reduce_sum(acc0);
    acc1 = wave_reduce_sum(acc1);
    if (lane == 0) {
      ulds[2 * w] = (1.0f / NN) / (acc0 + EPSC);
      ulds[2 * w + 1] = (1.0f / NN) / (acc1 + EPSC);
    }
  }
  __syncthreads();
  float ca[16];
#pragma unroll
  for (int j = 0; j < 16; j++) ca[j] = 0.f;
#pragma unroll
  for (int r = 0; r < 8; r++) {
    uint4 k = *(const uint4*)&ks[r * NN + tid * 16];
    float kd[16];
    fp8x16_decode(k, kd);
    float ur = ulds[r];
#pragma unroll
    for (int j = 0; j < 16; j++) ca[j] += kd[j] * ur;
  }
  float* pd = partial + (size_t)bid * NN + tid * 16;
#pragma unroll
  for (int q = 0; q < 4; q++)
    *(f32x4*)&pd[q * 4] = (f32x4){ca[q * 4], ca[q * 4 + 1], ca[q * 4 + 2], ca[q * 4 + 3]};
}

// grid dim3(64,3), block 256: v = nu/(sum over 512 partials + eps); 4 lane-groups x 128 summands
__global__ __launch_bounds__(256) void vcalc_kernel(const float* __restrict__ partial, float* __restrict__ v) {
  int p = blockIdx.y;
  int c = (threadIdx.x & 63);
  int g = threadIdx.x >> 6;
  const float* pp = partial + ((size_t)p * 512 + g * 128) * NN + blockIdx.x * 64 + c;
  float s = 0.f;
#pragma unroll 8
  for (int i = 0; i < 128; i++) s += pp[(size_t)i * NN];
  __shared__ float red[4][64];
  red[g][c] = s;
  __syncthreads();
  if (threadIdx.x < 64) {
    float t = red[0][threadIdx.x] + red[1][threadIdx.x] + red[2][threadIdx.x] + red[3][threadIdx.x];
    v[p * NN + blockIdx.x * 64 + threadIdx.x] = (1.0f / NN) * __builtin_amdgcn_rcpf(t + EPSC);
  }
}

// grid 1536 (p*512+rb), block 256, 8 rows/block, single pass:
//   per row: s1 = K·v, s2 = K·v·lnK; u = mu/(s1+eps); loss_row = u*(-REG)*s2
__global__ __launch_bounds__(256, 3) void loss_fused(const unsigned char* __restrict__ K,
                                                     const float* __restrict__ v, float* __restrict__ out) {
  int bid = blockIdx.x;
  int p = bid >> 9;
  int rb = bid & 511;
  int tid = threadIdx.x, w = tid >> 6, lane = tid & 63;
  __shared__ __align__(16) unsigned char ks[8 * NN];
  const unsigned char* Kp = K + (size_t)p * NN * NN;
  int r0 = rb * 8;
  {
    const unsigned char* g = Kp + (size_t)r0 * NN + w * 8192 + lane * 16;
#pragma unroll
    for (int i = 0; i < 8; i++)
      async_ld16(g + i * 1024, &ks[w * 8192 + i * 1024]);
  }
  __syncthreads();
  const float* vp = v + p * NN;
  float s1a = 0.f, s2a = 0.f, s1b = 0.f, s2b = 0.f;
#pragma unroll
  for (int c = 0; c < 4; c++) {
    uint4 k0 = *(const uint4*)&ks[(2 * w) * NN + c * 1024 + lane * 16];
    uint4 k1 = *(const uint4*)&ks[(2 * w + 1) * NN + c * 1024 + lane * 16];
    const float* vb = vp + c * 1024 + lane * 16;
    f32x4 v0 = *(const f32x4*)(vb + 0);
    f32x4 v1 = *(const f32x4*)(vb + 4);
    f32x4 v2 = *(const f32x4*)(vb + 8);
    f32x4 v3 = *(const f32x4*)(vb + 12);
    dot16v_dual(k0, v0, v1, v2, v3, s1a, s2a);
    dot16v_dual(k1, v0, v1, v2, v3, s1b, s2b);
  }
  s1a = wave_reduce_sum(s1a);
  s2a = wave_reduce_sum(s2a);
  s1b = wave_reduce_sum(s1b);
  s2b = wave_reduce_sum(s2b);
  float ua = (1.0f / NN) / (s1a + EPSC);
  float ub = (1.0f / NN) / (s1b + EPSC);
  float lt = ua * (-REGC) * s2a + ub * (-REGC) * s2b;
  __shared__ float red[4];
  if (lane == 0) red[w] = lt;
  __syncthreads();
  if (tid == 0) atomicAdd(out, (red[0] + red[1] + red[2] + red[3]) * (1.0f / 3.0f));
}

extern "C" void kernel_launch(void* const* d_in, const int* in_sizes, int n_in,
                              void* d_out, int out_size, void* d_ws, size_t ws_size,
                              hipStream_t stream) {
  const float* z0 = (const float*)d_in[0];
  const float* z1 = (const float*)d_in[1];
  const float* z2 = (const float*)d_in[2];
  float* out = (float*)d_out;
  char* ws = (char*)d_ws;

  const size_t K_BYTES = (size_t)3 * NN * NN;            // 50331648 (fp8)
  unsigned char* K = (unsigned char*)ws;
  short* zb = (short*)(ws + K_BYTES);                    // 3145728 B
  float* sq = (float*)(ws + K_BYTES + 3145728);          // 49152 B
  float* v = (float*)(ws + K_BYTES + 3145728 + 49152);   // 49152 B
  float* cpart = (float*)(ws + K_BYTES + 3145728 + 2 * 49152);   // 3*32*4096*4 = 1572864 B
  float* partial = (float*)(ws + K_BYTES + 3145728 + 2 * 49152 + 1572864);  // 3*512*4096*4 = 25.2 MB

  hipMemsetAsync(d_out, 0, sizeof(float), stream);

  prep_kernel<<<3 * NN, 128, 0, stream>>>(z0, z1, z2, zb, sq);
  kbuild_kernel<<<dim3(32, 32, 3), 256, 0, stream>>>(zb, sq, K, cpart);
  vinit_kernel<<<dim3(16, 3), 256, 0, stream>>>(cpart, v);

  for (int it = 0; it < NSINK; it++) {
    sink_fused<<<1536, 256, 0, stream>>>(K, v, partial);
    vcalc_kernel<<<dim3(64, 3), 256, 0, stream>>>(partial, v);
  }
  loss_fused<<<1536, 256, 0, stream>>>(K, v, out);
}

// Round 9
// 239.611 us; speedup vs baseline: 14.6415x; 1.4052x over previous
//
#include <hip/hip_runtime.h>

#define NN 4096
#define DD 128
#define REGC 0.05f
#define EPSC 1e-8f
#define NSINK 3
#define KPAD2 136   // shorts; 272B row stride, keeps 16B row alignment

typedef float f32x4 __attribute__((ext_vector_type(4)));
typedef float f32x2 __attribute__((ext_vector_type(2)));
typedef short s16x8 __attribute__((ext_vector_type(8)));

__device__ __forceinline__ float wave_reduce_sum(float s) {
#pragma unroll
  for (int m = 32; m >= 1; m >>= 1) s += __shfl_xor(s, m, 64);
  return s;
}

__device__ __forceinline__ short f32_to_bf16(float f) {
  union { float f; unsigned u; } x; x.f = f;
  unsigned r = (x.u + 0x7FFFu + ((x.u >> 16) & 1u)) >> 16;
  return (short)r;
}

__device__ __forceinline__ void fp8x4_decode(unsigned int k, float* o) {
  f32x2 lo = __builtin_amdgcn_cvt_pk_f32_fp8((int)k, false);
  f32x2 hi = __builtin_amdgcn_cvt_pk_f32_fp8((int)k, true);
  o[0] = lo[0]; o[1] = lo[1]; o[2] = hi[0]; o[3] = hi[1];
}

__device__ __forceinline__ void fp8x16_decode(uint4 k, float* o) {
  fp8x4_decode(k.x, o); fp8x4_decode(k.y, o + 4);
  fp8x4_decode(k.z, o + 8); fp8x4_decode(k.w, o + 12);
}

__device__ __forceinline__ float dot16v(uint4 k, f32x4 v0, f32x4 v1, f32x4 v2, f32x4 v3) {
  float o[16];
  fp8x16_decode(k, o);
  float s = 0.f;
#pragma unroll
  for (int j = 0; j < 4; j++) s += o[j] * v0[j];
#pragma unroll
  for (int j = 0; j < 4; j++) s += o[4 + j] * v1[j];
#pragma unroll
  for (int j = 0; j < 4; j++) s += o[8 + j] * v2[j];
#pragma unroll
  for (int j = 0; j < 4; j++) s += o[12 + j] * v3[j];
  return s;
}

// dual accumulate: s1 += K*v, s2 += K*v*ln(K)   (loss C = -REG*lnK factored out)
__device__ __forceinline__ void dot16v_dual(uint4 k, f32x4 v0, f32x4 v1, f32x4 v2, f32x4 v3,
                                            float& s1, float& s2) {
  float o[16];
  fp8x16_decode(k, o);
#pragma unroll
  for (int q = 0; q < 4; q++) {
    f32x4 vv = (q == 0) ? v0 : (q == 1) ? v1 : (q == 2) ? v2 : v3;
#pragma unroll
    for (int j = 0; j < 4; j++) {
      float kf = o[q * 4 + j];
      float kv = kf * vv[j];
      s1 += kv;
      s2 += kv * __logf(fmaxf(kf, 1e-6f));
    }
  }
}

// async global->LDS, 16B per lane; LDS slot = uniform base + lane*16
__device__ __forceinline__ void async_ld16(const unsigned char* g, unsigned char* l) {
  __builtin_amdgcn_global_load_lds((const __attribute__((address_space(1))) void*)g,
                                   (__attribute__((address_space(3))) void*)l, 16, 0, 0);
}

// grid 12288 (zi*4096+row), block 128: row norms + bf16 convert
__global__ __launch_bounds__(128) void prep_kernel(const float* __restrict__ z0, const float* __restrict__ z1,
                                                   const float* __restrict__ z2, short* __restrict__ zb,
                                                   float* __restrict__ sq) {
  int row = blockIdx.x;
  int zi = row >> 12;
  const float* z = (zi == 0) ? z0 : ((zi == 1) ? z1 : z2);
  int r = row & (NN - 1);
  float val = z[r * DD + threadIdx.x];
  zb[row * DD + threadIdx.x] = f32_to_bf16(val);
  float s = wave_reduce_sum(val * val);
  __shared__ float red[2];
  if ((threadIdx.x & 63) == 0) red[threadIdx.x >> 6] = s;
  __syncthreads();
  if (threadIdx.x == 0) sq[row] = red[0] + red[1];
}

// grid dim3(32,32,3), block 256. K rows = x (blockIdx.y), K cols = y (blockIdx.x).
// A operand = y (LDS), B operand = x (global) -> lane's 4 acc regs horizontal in K ->
// pack u32 -> padded LDS tile -> full-line stores. Col sums -> cpart[(p*32+by)*NN + bx*128+col].
__global__ __launch_bounds__(256, 3) void kbuild_kernel(const short* __restrict__ zb, const float* __restrict__ sq,
                                                        unsigned char* __restrict__ K, float* __restrict__ cpart) {
  int p = blockIdx.z;
  int ai = (p == 2) ? 1 : 0;            // pairs (0,1),(0,2),(1,2)
  int bi = (p == 0) ? 1 : 2;
  const short* xg = zb + ai * NN * DD + blockIdx.y * 128 * DD;   // B operand (K rows)
  const short* yg = zb + bi * NN * DD + blockIdx.x * 128 * DD;   // A operand (K cols), staged
  const float* sqx = sq + ai * NN + blockIdx.y * 128;
  const float* sqy = sq + bi * NN + blockIdx.x * 128;
  __shared__ __align__(16) unsigned char smem[128 * KPAD2 * 2];  // ys, later aliased by kt
  __shared__ float colsum[128];
  short* ys = (short*)smem;
  unsigned int* kt = (unsigned int*)smem;   // [128][36] u32, row stride 144B
  int tid = threadIdx.x;
  for (int i = tid; i < 2048; i += 256) {
    int row = i >> 4, seg = i & 15;
    *(uint4*)&ys[row * KPAD2 + seg * 8] = *(const uint4*)&yg[row * DD + seg * 8];
  }
  if (tid < 128) colsum[tid] = 0.f;
  __syncthreads();
  int w = tid >> 6, lane = tid & 63;
  int wy = (w >> 1) * 64, wx = (w & 1) * 64;   // y(col) / x(row) quadrants
  int lrow = lane & 15, lk = lane >> 4;
  f32x4 acc[4][4];   // [yt][xt]
#pragma unroll
  for (int i = 0; i < 4; i++)
#pragma unroll
    for (int j = 0; j < 4; j++) acc[i][j] = (f32x4){0.f, 0.f, 0.f, 0.f};
#pragma unroll
  for (int kk = 0; kk < 4; kk++) {
    s16x8 a[4], b[4];
#pragma unroll
    for (int t = 0; t < 4; t++) {
      a[t] = *(const s16x8*)&ys[(wy + t * 16 + lrow) * KPAD2 + kk * 32 + lk * 8];
      b[t] = *(const s16x8*)&xg[(wx + t * 16 + lrow) * DD + kk * 32 + lk * 8];
    }
#pragma unroll
    for (int yt = 0; yt < 4; yt++)
#pragma unroll
      for (int xt = 0; xt < 4; xt++)
        acc[yt][xt] = __builtin_amdgcn_mfma_f32_16x16x32_bf16(a[yt], b[xt], acc[yt][xt], 0, 0, 0);
  }
  unsigned int pk[4][4];   // [xt][yt] packed 4 consecutive K-cols
  float csum[4][4];        // [yt][r]
#pragma unroll
  for (int i = 0; i < 4; i++)
#pragma unroll
    for (int j = 0; j < 4; j++) csum[i][j] = 0.f;
#pragma unroll
  for (int xt = 0; xt < 4; xt++) {
    int xl = wx + xt * 16 + lrow;
    float sx = sqx[xl];
#pragma unroll
    for (int yt = 0; yt < 4; yt++) {
      int yl0 = wy + yt * 16 + lk * 4;
      float kf[4];
#pragma unroll
      for (int r = 0; r < 4; r++) {
        float Cv = fmaxf(sx + sqy[yl0 + r] - 2.0f * acc[yt][xt][r], 0.0f);
        kf[r] = __expf(Cv * (-1.0f / REGC));
        csum[yt][r] += kf[r];
      }
      int pw = __builtin_amdgcn_cvt_pk_fp8_f32(kf[0], kf[1], 0, false);
      pw = __builtin_amdgcn_cvt_pk_fp8_f32(kf[2], kf[3], pw, true);
      pk[xt][yt] = (unsigned int)pw;
    }
  }
#pragma unroll
  for (int yt = 0; yt < 4; yt++)
#pragma unroll
    for (int r = 0; r < 4; r++) {
      float s = csum[yt][r];
      s += __shfl_xor(s, 1, 64); s += __shfl_xor(s, 2, 64);
      s += __shfl_xor(s, 4, 64); s += __shfl_xor(s, 8, 64);
      if (lrow == 0) atomicAdd(&colsum[wy + yt * 16 + lk * 4 + r], s);
    }
  __syncthreads();   // done reading ys; safe to alias with kt
#pragma unroll
  for (int xt = 0; xt < 4; xt++) {
    int xl = wx + xt * 16 + lrow;
#pragma unroll
    for (int yt = 0; yt < 4; yt++)
      kt[xl * 36 + ((wy + yt * 16) >> 2) + lk] = pk[xt][yt];
  }
  __syncthreads();
  unsigned char* Kb = K + (size_t)p * NN * NN + (size_t)blockIdx.y * 128 * NN + blockIdx.x * 128;
#pragma unroll
  for (int rd = 0; rd < 4; rd++) {
    int rl = (tid >> 3) + rd * 32;
    int ch = tid & 7;
    uint4 d = *(const uint4*)&kt[rl * 36 + ch * 4];
    *(uint4*)(Kb + (size_t)rl * NN + ch * 16) = d;
  }
  if (tid < 128)
    cpart[(size_t)(p * 32 + blockIdx.y) * NN + blockIdx.x * 128 + tid] = colsum[tid];
}

// grid dim3(16,3), block 256: v = nu/(sum_by cpart + eps)  (initial v for u0=1)
__global__ __launch_bounds__(256) void vinit_kernel(const float* __restrict__ cpart, float* __restrict__ v) {
  int p = blockIdx.y;
  int col = blockIdx.x * 256 + threadIdx.x;
  float s = 0.f;
#pragma unroll 8
  for (int by = 0; by < 32; by++) s += cpart[(size_t)(p * 32 + by) * NN + col];
  v[p * NN + col] = (1.0f / NN) * __builtin_amdgcn_rcpf(s + EPSC);
}

// grid 1536 (p*512+rb), block 256 (4 waves), 8 rows/block:
//   A: async-DMA the block's 8 K rows (32 KB) into LDS
//   B: wave w: rows 2w,2w+1: u = mu/(K v + eps); v read from global (L1/L2-hot)
//   C: thread owns 16 cols over 8 rows (from LDS); partial stored vcalc-friendly:
//      partial[((p*256 + tid)*512 + rb)*16 + j]  -> 64B contiguous per thread
__global__ __launch_bounds__(256, 3) void sink_fused(const unsigned char* __restrict__ K,
                                                     const float* __restrict__ v, float* __restrict__ partial) {
  int bid = blockIdx.x;
  int p = bid >> 9;
  int rb = bid & 511;
  int tid = threadIdx.x, w = tid >> 6, lane = tid & 63;
  __shared__ __align__(16) unsigned char ks[8 * NN];
  __shared__ float ulds[8];
  const unsigned char* Kp = K + (size_t)p * NN * NN;
  int r0 = rb * 8;
  {
    const unsigned char* g = Kp + (size_t)r0 * NN + w * 8192 + lane * 16;
#pragma unroll
    for (int i = 0; i < 8; i++)
      async_ld16(g + i * 1024, &ks[w * 8192 + i * 1024]);
  }
  __syncthreads();
  const float* vp = v + p * NN;
  {
    float acc0 = 0.f, acc1 = 0.f;
#pragma unroll
    for (int c = 0; c < 4; c++) {
      uint4 k0 = *(const uint4*)&ks[(2 * w) * NN + c * 1024 + lane * 16];
      uint4 k1 = *(const uint4*)&ks[(2 * w + 1) * NN + c * 1024 + lane * 16];
      const float* vb = vp + c * 1024 + lane * 16;
      f32x4 v0 = *(const f32x4*)(vb + 0);
      f32x4 v1 = *(const f32x4*)(vb + 4);
      f32x4 v2 = *(const f32x4*)(vb + 8);
      f32x4 v3 = *(const f32x4*)(vb + 12);
      acc0 += dot16v(k0, v0, v1, v2, v3);
      acc1 += dot16v(k1, v0, v1, v2, v3);
    }
    acc0 = wave_reduce_sum(acc0);
    acc1 = wave_reduce_sum(acc1);
    if (lane == 0) {
      ulds[2 * w] = (1.0f / NN) / (acc0 + EPSC);
      ulds[2 * w + 1] = (1.0f / NN) / (acc1 + EPSC);
    }
  }
  __syncthreads();
  float ca[16];
#pragma unroll
  for (int j = 0; j < 16; j++) ca[j] = 0.f;
#pragma unroll
  for (int r = 0; r < 8; r++) {
    uint4 k = *(const uint4*)&ks[r * NN + tid * 16];
    float kd[16];
    fp8x16_decode(k, kd);
    float ur = ulds[r];
#pragma unroll
    for (int j = 0; j < 16; j++) ca[j] += kd[j] * ur;
  }
  float* pd = partial + (((size_t)p * 256 + tid) * 512 + rb) * 16;
#pragma unroll
  for (int q = 0; q < 4; q++)
    *(f32x4*)&pd[q * 4] = (f32x4){ca[q * 4], ca[q * 4 + 1], ca[q * 4 + 2], ca[q * 4 + 3]};
}

// grid dim3(256,3), block 256: col-chunk cc owns 16 cols; its 512 summand-chunks are a
// CONTIGUOUS 32 KB run. v[cc*16+j] = nu/(sum + eps).
__global__ __launch_bounds__(256) void vcalc_kernel(const float* __restrict__ partial, float* __restrict__ v) {
  int p = blockIdx.y;
  int cc = blockIdx.x;
  int tid = threadIdx.x, w = tid >> 6, lane = tid & 63;
  const float* base = partial + ((size_t)p * 256 + cc) * 512 * 16;
  f32x4 a0 = {0.f, 0.f, 0.f, 0.f}, a1 = a0, a2 = a0, a3 = a0;
#pragma unroll 2
  for (int i = tid; i < 512; i += 256) {
    const float* q = base + (size_t)i * 16;
    a0 += *(const f32x4*)(q + 0);
    a1 += *(const f32x4*)(q + 4);
    a2 += *(const f32x4*)(q + 8);
    a3 += *(const f32x4*)(q + 12);
  }
#pragma unroll
  for (int m = 32; m >= 1; m >>= 1) {
#pragma unroll
    for (int j = 0; j < 4; j++) {
      a0[j] += __shfl_xor(a0[j], m, 64);
      a1[j] += __shfl_xor(a1[j], m, 64);
      a2[j] += __shfl_xor(a2[j], m, 64);
      a3[j] += __shfl_xor(a3[j], m, 64);
    }
  }
  __shared__ float red[4][16];
  if (lane == 0) {
#pragma unroll
    for (int j = 0; j < 4; j++) {
      red[w][j] = a0[j]; red[w][4 + j] = a1[j];
      red[w][8 + j] = a2[j]; red[w][12 + j] = a3[j];
    }
  }
  __syncthreads();
  if (tid < 16) {
    float s = red[0][tid] + red[1][tid] + red[2][tid] + red[3][tid];
    v[p * NN + cc * 16 + tid] = (1.0f / NN) * __builtin_amdgcn_rcpf(s + EPSC);
  }
}

// grid 1536 (p*512+rb), block 256, 8 rows/block, single pass:
//   per row: s1 = K·v, s2 = K·v·lnK; u = mu/(s1+eps); loss_row = u*(-REG)*s2
__global__ __launch_bounds__(256, 3) void loss_fused(const unsigned char* __restrict__ K,
                                                     const float* __restrict__ v, float* __restrict__ out) {
  int bid = blockIdx.x;
  int p = bid >> 9;
  int rb = bid & 511;
  int tid = threadIdx.x, w = tid >> 6, lane = tid & 63;
  __shared__ __align__(16) unsigned char ks[8 * NN];
  const unsigned char* Kp = K + (size_t)p * NN * NN;
  int r0 = rb * 8;
  {
    const unsigned char* g = Kp + (size_t)r0 * NN + w * 8192 + lane * 16;
#pragma unroll
    for (int i = 0; i < 8; i++)
      async_ld16(g + i * 1024, &ks[w * 8192 + i * 1024]);
  }
  __syncthreads();
  const float* vp = v + p * NN;
  float s1a = 0.f, s2a = 0.f, s1b = 0.f, s2b = 0.f;
#pragma unroll
  for (int c = 0; c < 4; c++) {
    uint4 k0 = *(const uint4*)&ks[(2 * w) * NN + c * 1024 + lane * 16];
    uint4 k1 = *(const uint4*)&ks[(2 * w + 1) * NN + c * 1024 + lane * 16];
    const float* vb = vp + c * 1024 + lane * 16;
    f32x4 v0 = *(const f32x4*)(vb + 0);
    f32x4 v1 = *(const f32x4*)(vb + 4);
    f32x4 v2 = *(const f32x4*)(vb + 8);
    f32x4 v3 = *(const f32x4*)(vb + 12);
    dot16v_dual(k0, v0, v1, v2, v3, s1a, s2a);
    dot16v_dual(k1, v0, v1, v2, v3, s1b, s2b);
  }
  s1a = wave_reduce_sum(s1a);
  s2a = wave_reduce_sum(s2a);
  s1b = wave_reduce_sum(s1b);
  s2b = wave_reduce_sum(s2b);
  float ua = (1.0f / NN) / (s1a + EPSC);
  float ub = (1.0f / NN) / (s1b + EPSC);
  float lt = ua * (-REGC) * s2a + ub * (-REGC) * s2b;
  __shared__ float red[4];
  if (lane == 0) red[w] = lt;
  __syncthreads();
  if (tid == 0) atomicAdd(out, (red[0] + red[1] + red[2] + red[3]) * (1.0f / 3.0f));
}

extern "C" void kernel_launch(void* const* d_in, const int* in_sizes, int n_in,
                              void* d_out, int out_size, void* d_ws, size_t ws_size,
                              hipStream_t stream) {
  const float* z0 = (const float*)d_in[0];
  const float* z1 = (const float*)d_in[1];
  const float* z2 = (const float*)d_in[2];
  float* out = (float*)d_out;
  char* ws = (char*)d_ws;

  const size_t K_BYTES = (size_t)3 * NN * NN;            // 50331648 (fp8)
  unsigned char* K = (unsigned char*)ws;
  short* zb = (short*)(ws + K_BYTES);                    // 3145728 B
  float* sq = (float*)(ws + K_BYTES + 3145728);          // 49152 B
  float* v = (float*)(ws + K_BYTES + 3145728 + 49152);   // 49152 B
  float* cpart = (float*)(ws + K_BYTES + 3145728 + 2 * 49152);   // 1572864 B
  float* partial = (float*)(ws + K_BYTES + 3145728 + 2 * 49152 + 1572864);  // 3*256*512*16*4 = 25.2 MB

  hipMemsetAsync(d_out, 0, sizeof(float), stream);

  prep_kernel<<<3 * NN, 128, 0, stream>>>(z0, z1, z2, zb, sq);
  kbuild_kernel<<<dim3(32, 32, 3), 256, 0, stream>>>(zb, sq, K, cpart);
  vinit_kernel<<<dim3(16, 3), 256, 0, stream>>>(cpart, v);

  for (int it = 0; it < NSINK; it++) {
    sink_fused<<<1536, 256, 0, stream>>>(K, v, partial);
    vcalc_kernel<<<dim3(256, 3), 256, 0, stream>>>(partial, v);
  }
  // loss folds the final u-half-step (effectively NSINK + 0.5 iterations)
  loss_fused<<<1536, 256, 0, stream>>>(K, v, out);
}